// Round 7
// baseline (6023.755 us; speedup 1.0000x reference)
//
#include <hip/hip_runtime.h>

typedef short s16x8 __attribute__((ext_vector_type(8)));
typedef float f32x4 __attribute__((ext_vector_type(4)));

constexpr int B_  = 128;
constexpr int T_  = 152;
constexpr int I_  = 75;
constexpr int H_  = 256;
constexpr int L_  = 16;
constexpr int C_  = 625;
constexpr int G4  = 1024;          // 4*H
constexpr float EPS_ = 1e-5f;
constexpr int NBLK = 256;          // 16 layers x 16 col-groups
constexpr int ND  = T_ + L_ - 1;   // 167 diagonals
constexpr int NMAT2 = 32;          // 15 W_ih + 16 W_hh + 1 W0^T(padded)
constexpr size_t MATSZ = (size_t)G4 * H_;
constexpr int HDEP = 8;            // H rotation depth (WAR slack 7)

constexpr int WSTRIDE = 266;               // 133 dwords, odd mod 32 -> <=2-way LDS conflicts
constexpr int WPL_SH  = 64 * WSTRIDE;      // shorts per W plane in LDS (17024)
constexpr int DYNLDS  = 4 * WPL_SH * 2;    // 136192 B dynamic arena
constexpr int FLAGSTR = 32;                // u32 per flag slot (128B line)
constexpr int XK      = 96;                // padded K for layer-0 input (75 -> 96)

__device__ __forceinline__ f32x4 mfma16(s16x8 a, s16x8 b, f32x4 c) {
    return __builtin_amdgcn_mfma_f32_16x16x32_bf16(a, b, c, 0, 0, 0);
}
__device__ __forceinline__ float sigm(float x) { return 1.f / (1.f + expf(-x)); }
__device__ __forceinline__ short f2bf(float x) {
    __bf16 h = (__bf16)x; return __builtin_bit_cast(short, h);
}
__device__ __forceinline__ float bf2f(short s) {
    __bf16 h = __builtin_bit_cast(__bf16, s); return (float)h;
}

// ---------------------------------------------------------------------------
// Prep kernels (transpose + hi/lo bf16 split)
// ---------------------------------------------------------------------------
__global__ void __launch_bounds__(256)
prep_kernel(const float* __restrict__ Wih, const float* __restrict__ Whh,
            short* __restrict__ Wth, short* __restrict__ Wtl) {
    __shared__ float tile[64][65];
    const int mat = blockIdx.z;
    const int n0  = blockIdx.x * 64;
    const int k0  = blockIdx.y * 64;
    const int tid = threadIdx.x;
    const float* src = (mat < 15) ? (Wih + (size_t)mat * MATSZ)
                                  : (Whh + (size_t)(mat - 15) * MATSZ);
#pragma unroll
    for (int r = 0; r < 16; ++r) {
        int idx = r * 256 + tid;
        int kk = idx >> 6, nn = idx & 63;
        tile[kk][nn] = src[(size_t)(k0 + kk) * G4 + n0 + nn];
    }
    __syncthreads();
#pragma unroll
    for (int r = 0; r < 16; ++r) {
        int idx = r * 256 + tid;
        int nn = idx >> 6, kk = idx & 63;
        float w = tile[kk][nn];
        short hi = f2bf(w);
        short lo = f2bf(w - bf2f(hi));
        size_t o = ((size_t)mat * G4 + n0 + nn) * H_ + k0 + kk;
        Wth[o] = hi;
        Wtl[o] = lo;
    }
}

__global__ void __launch_bounds__(256)
prep_w0(const float* __restrict__ Wih0, short* __restrict__ Wth, short* __restrict__ Wtl) {
    const int n = blockIdx.x;
    const int k = threadIdx.x;
    float w = (k < I_) ? Wih0[(size_t)k * G4 + n] : 0.f;
    short hi = f2bf(w);
    short lo = f2bf(w - bf2f(hi));
    size_t o = ((size_t)31 * G4 + n) * H_ + k;
    Wth[o] = hi;
    Wtl[o] = lo;
}

__global__ void __launch_bounds__(256)
prep_x(const float* __restrict__ seq, short* __restrict__ Xph, short* __restrict__ Xpl) {
    const int t = blockIdx.x;
    for (int idx = threadIdx.x; idx < B_ * XK; idx += 256) {
        int row = idx / XK, k = idx - row * XK;
        float v = (k < I_) ? seq[(size_t)row * T_ * I_ + (size_t)t * I_ + k] : 0.f;
        short hi = f2bf(v);
        short lo = f2bf(v - bf2f(hi));
        size_t o = ((size_t)t * B_ + row) * XK + k;
        Xph[o] = hi;
        Xpl[o] = lo;
    }
}

// BN stats for 8 groups (4 input gates, 4 recurrent), 8 waves (16-row tiles).
__device__ __forceinline__ void bn_stats8(
    const f32x4 aI[4], const f32x4 aR[4], int tid,
    float (*redS)[8][16], float (*redQ)[8][16],   // [8][8][16]
    float (*mvM)[16], float (*mvI)[16]) {         // [8][16]
    const int lane = tid & 63;
    const int wv   = tid >> 6;
    const int lcol = lane & 15;
#pragma unroll
    for (int g = 0; g < 8; ++g) {
        const f32x4& v = (g < 4) ? aI[g] : aR[g - 4];
        float s = 0.f, q = 0.f;
#pragma unroll
        for (int r = 0; r < 4; ++r) { float a = v[r]; s += a; q += a * a; }
        s += __shfl_xor(s, 16); s += __shfl_xor(s, 32);
        q += __shfl_xor(q, 16); q += __shfl_xor(q, 32);
        if (lane < 16) { redS[g][wv][lcol] = s; redQ[g][wv][lcol] = q; }
    }
    __syncthreads();
    if (tid < 128) {
        int g = tid >> 4, c = tid & 15;
        float s = 0.f, q = 0.f;
#pragma unroll
        for (int w = 0; w < 8; ++w) { s += redS[g][w][c]; q += redQ[g][w][c]; }
        float m = s * (1.0f / B_);
        float v = q * (1.0f / B_) - m * m;
        mvM[g][c] = m;
        mvI[g][c] = rsqrtf(fmaxf(v, 0.f) + EPS_);
    }
    __syncthreads();
}

// ---------------------------------------------------------------------------
// Wavefront kernel: 256 WGs x 512 threads (8 waves -> 2/SIMD TLP).
// Persistent W in LDS; p2p flags; parallel 3-lane polling; depth-8 H rotation.
// ---------------------------------------------------------------------------
__global__ void __launch_bounds__(512, 1)
wave_kernel(const short* __restrict__ Wth, const short* __restrict__ Wtl,
            const short* __restrict__ Xph, const short* __restrict__ Xpl,
            const float* __restrict__ bias,
            const float* __restrict__ g_ih, const float* __restrict__ b_ih,
            const float* __restrict__ g_hh, const float* __restrict__ b_hh,
            const float* __restrict__ g_c,  const float* __restrict__ b_c,
            short* __restrict__ Hh, short* __restrict__ Hl,
            unsigned* __restrict__ flags) {
    extern __shared__ char arena[];
    __shared__ float redS[8][8][16];
    __shared__ float redQ[8][8][16];
    __shared__ float mvM[8][16], mvI[8][16];
    __shared__ float cms[16], cis[16];

    short* Wr_hi = (short*)arena;
    short* Wr_lo = Wr_hi + WPL_SH;
    short* Wi_hi = Wr_lo + WPL_SH;
    short* Wi_lo = Wi_hi + WPL_SH;

    const int b    = blockIdx.x;
    const int l    = ((b & 7) << 1) | ((b >> 3) & 1);  // layers 2x,2x+1 per XCD
    const int gq   = b >> 4;
    const int j0   = gq * 16;
    const int tid  = threadIdx.x;
    const int lane = tid & 63;
    const int wv   = tid >> 6;          // 0..7: 16-row M-tile
    const int quad = lane >> 4;
    const int lcol = lane & 15;
    const int jc   = j0 + lcol;

    float gihv[4], bihv[4], ghhv[4], bhhv[4], bsv[4];
#pragma unroll
    for (int g = 0; g < 4; ++g) {
        int col = l * G4 + g * H_ + jc;
        gihv[g] = g_ih[col];
        bihv[g] = b_ih[col];
        ghhv[g] = g_hh[col];
        bhhv[g] = b_hh[col];
        bsv[g]  = bias[col];
    }
    const float gcv = g_c[l * H_ + jc];
    const float bcv = b_c[l * H_ + jc];

    // ---- persistent weight preload (once) ----
    {
        const int row = tid >> 3, seg = (tid & 7) * 32;
        const int g = row >> 4, c = row & 15;
        const size_t srow = ((size_t)(g * H_ + j0 + c)) * H_ + seg;
        const int miI = (l > 0) ? (l - 1) : 31;
        const short* sWrh = Wth + (size_t)(15 + l) * MATSZ + srow;
        const short* sWrl = Wtl + (size_t)(15 + l) * MATSZ + srow;
        const short* sWih = Wth + (size_t)miI * MATSZ + srow;
        const short* sWil = Wtl + (size_t)miI * MATSZ + srow;
        short* dWrh = Wr_hi + row * WSTRIDE + seg;
        short* dWrl = Wr_lo + row * WSTRIDE + seg;
        short* dWih = Wi_hi + row * WSTRIDE + seg;
        short* dWil = Wi_lo + row * WSTRIDE + seg;
#pragma unroll
        for (int u = 0; u < 4; ++u) {
            *(s16x8*)(dWrh + u * 8) = *(const s16x8*)(sWrh + u * 8);
            *(s16x8*)(dWrl + u * 8) = *(const s16x8*)(sWrl + u * 8);
            *(s16x8*)(dWih + u * 8) = *(const s16x8*)(sWih + u * 8);
            *(s16x8*)(dWil + u * 8) = *(const s16x8*)(sWil + u * 8);
        }
    }
    __syncthreads();

    f32x4 creg;
    creg = (f32x4){0.f, 0.f, 0.f, 0.f};

    const int arow = wv * 16 + lcol;    // A row (m = lcol within tile wv)
    const int koff = quad * 8;

    for (int t = 0; t < T_; ++t) {
        const int d  = t + l;
        const int pr = (d - 1) & (HDEP - 1);
        const int pw = d & (HDEP - 1);

        // ---- wait: 3 lanes poll concurrently, acquire at end ----
        unsigned* fO = (t >= 1) ? &flags[(size_t)(l * ND + (d - 1)) * FLAGSTR] : nullptr;
        unsigned* fB = (l > 0)  ? &flags[(size_t)((l - 1) * ND + (d - 1)) * FLAGSTR] : nullptr;
        unsigned* fW = (l < 15 && t >= HDEP)
                       ? &flags[(size_t)((l + 1) * ND + (d - (HDEP - 1))) * FLAGSTR] : nullptr;
        if (tid < 3) {
            unsigned* f = (tid == 0) ? fO : (tid == 1) ? fB : fW;
            if (f) {
                while (__hip_atomic_load(f, __ATOMIC_RELAXED,
                                         __HIP_MEMORY_SCOPE_AGENT) < 16u) {}
                (void)__hip_atomic_load(f, __ATOMIC_ACQUIRE, __HIP_MEMORY_SCOPE_AGENT);
            }
        }
        __syncthreads();

        // ---- fused K-loop: rec + input GEMMs, W from LDS, A from global ----
        f32x4 accI[4], accR[4];
#pragma unroll
        for (int g = 0; g < 4; ++g) {
            accI[g] = (f32x4){0.f, 0.f, 0.f, 0.f};
            accR[g] = (f32x4){0.f, 0.f, 0.f, 0.f};
        }

        const short* XRh = Hh + (size_t)(l * HDEP + pr) * B_ * H_;
        const short* XRl = Hl + (size_t)(l * HDEP + pr) * B_ * H_;
        const short* XIh; const short* XIl; int xis, ksI;
        if (l > 0) {
            XIh = Hh + (size_t)((l - 1) * HDEP + pr) * B_ * H_;
            XIl = Hl + (size_t)((l - 1) * HDEP + pr) * B_ * H_;
            xis = H_; ksI = 8;
        } else {
            XIh = Xph + (size_t)t * B_ * XK;
            XIl = Xpl + (size_t)t * B_ * XK;
            xis = XK; ksI = 3;
        }

#pragma unroll
        for (int ks = 0; ks < 8; ++ks) {
            const int ko = ks * 32 + koff;
            s16x8 arh = *(const s16x8*)&XRh[(size_t)arow * H_ + ko];
            s16x8 arl = *(const s16x8*)&XRl[(size_t)arow * H_ + ko];
            const bool doI = (ks < ksI);
            s16x8 aih{}, ail{};
            if (doI) {
                aih = *(const s16x8*)&XIh[(size_t)arow * xis + ko];
                ail = *(const s16x8*)&XIl[(size_t)arow * xis + ko];
            }
#pragma unroll
            for (int g = 0; g < 4; ++g) {
                const int bo = (g * 16 + lcol) * WSTRIDE + ko;
                s16x8 brh = *(const s16x8*)&Wr_hi[bo];
                s16x8 brl = *(const s16x8*)&Wr_lo[bo];
                accR[g] = mfma16(arh, brh, accR[g]);
                accR[g] = mfma16(arl, brh, accR[g]);
                accR[g] = mfma16(arh, brl, accR[g]);
                accR[g] = mfma16(arl, brl, accR[g]);
                if (doI) {
                    s16x8 bih = *(const s16x8*)&Wi_hi[bo];
                    s16x8 bil = *(const s16x8*)&Wi_lo[bo];
                    accI[g] = mfma16(aih, bih, accI[g]);
                    accI[g] = mfma16(ail, bih, accI[g]);
                    accI[g] = mfma16(aih, bil, accI[g]);
                    accI[g] = mfma16(ail, bil, accI[g]);
                }
            }
        }

        // ---- BN stats (both GEMMs, one pass) ----
        bn_stats8(accI, accR, tid, redS, redQ, mvM, mvI);

        f32x4 osv;
#pragma unroll
        for (int r = 0; r < 4; ++r) {
            float bn0 = (accI[0][r] - mvM[0][lcol]) * mvI[0][lcol] * gihv[0] + bihv[0];
            float bn1 = (accI[1][r] - mvM[1][lcol]) * mvI[1][lcol] * gihv[1] + bihv[1];
            float bn2 = (accI[2][r] - mvM[2][lcol]) * mvI[2][lcol] * gihv[2] + bihv[2];
            float bn3 = (accI[3][r] - mvM[3][lcol]) * mvI[3][lcol] * gihv[3] + bihv[3];
            float sf = (accR[0][r] - mvM[4][lcol]) * mvI[4][lcol] * ghhv[0] + bhhv[0] + bn0 + bsv[0];
            float si = (accR[1][r] - mvM[5][lcol]) * mvI[5][lcol] * ghhv[1] + bhhv[1] + bn1 + bsv[1];
            float so = (accR[2][r] - mvM[6][lcol]) * mvI[6][lcol] * ghhv[2] + bhhv[2] + bn2 + bsv[2];
            float sg = (accR[3][r] - mvM[7][lcol]) * mvI[7][lcol] * ghhv[3] + bhhv[3] + bn3 + bsv[3];
            creg[r] = sigm(sf) * creg[r] + sigm(si) * tanhf(sg);
            osv[r]  = so;
        }

        // ---- BN over c ----
        {
            float s = 0.f, q = 0.f;
#pragma unroll
            for (int r = 0; r < 4; ++r) { float a = creg[r]; s += a; q += a * a; }
            s += __shfl_xor(s, 16); s += __shfl_xor(s, 32);
            q += __shfl_xor(q, 16); q += __shfl_xor(q, 32);
            if (lane < 16) { redS[0][wv][lcol] = s; redQ[0][wv][lcol] = q; }
        }
        __syncthreads();
        if (tid < 16) {
            float s = 0.f, q = 0.f;
#pragma unroll
            for (int w = 0; w < 8; ++w) { s += redS[0][w][tid]; q += redQ[0][w][tid]; }
            float m = s * (1.0f / B_);
            float v = q * (1.0f / B_) - m * m;
            cms[tid] = m;
            cis[tid] = rsqrtf(fmaxf(v, 0.f) + EPS_);
        }
        __syncthreads();
        {
            const float m = cms[lcol], is = cis[lcol];
            short* Hwh = Hh + (size_t)(l * HDEP + pw) * B_ * H_;
            short* Hwl = Hl + (size_t)(l * HDEP + pw) * B_ * H_;
#pragma unroll
            for (int r = 0; r < 4; ++r) {
                int row = wv * 16 + quad * 4 + r;
                float hv = sigm(osv[r]) * tanhf((creg[r] - m) * is * gcv + bcv);
                short hi = f2bf(hv);
                short lo = f2bf(hv - bf2f(hi));
                __hip_atomic_store(&Hwh[(size_t)row * H_ + jc], hi,
                                   __ATOMIC_RELAXED, __HIP_MEMORY_SCOPE_AGENT);
                __hip_atomic_store(&Hwl[(size_t)row * H_ + jc], lo,
                                   __ATOMIC_RELAXED, __HIP_MEMORY_SCOPE_AGENT);
            }
        }
        __syncthreads();   // all threads' agent-scope stores issued & drained
        if (tid == 0)
            __hip_atomic_fetch_add(&flags[(size_t)(l * ND + d) * FLAGSTR], 1u,
                                   __ATOMIC_RELEASE, __HIP_MEMORY_SCOPE_AGENT);
    }
}

// ---------------------------------------------------------------------------
// Final linear + softmax: one WG per batch row.
// ---------------------------------------------------------------------------
__global__ void __launch_bounds__(256)
final_kernel(const short* __restrict__ Hh, const short* __restrict__ Hl,
             const float* __restrict__ Wlin, const float* __restrict__ blin,
             float* __restrict__ out) {
    const int b   = blockIdx.x;
    const int tid = threadIdx.x;
    __shared__ float hs[H_];
    __shared__ float rbuf[256];
    constexpr int lastPar = (ND - 1) & (HDEP - 1);  // = 6

    {
        size_t o = (size_t)((L_ - 1) * HDEP + lastPar) * B_ * H_ + (size_t)b * H_ + tid;
        hs[tid] = bf2f(Hh[o]) + bf2f(Hl[o]);
    }
    __syncthreads();

    float lg[3];
#pragma unroll
    for (int r = 0; r < 3; ++r) {
        int cls = tid + r * 256;
        float a = -1e30f;
        if (cls < C_) {
            a = blin[cls];
            for (int j = 0; j < H_; ++j) a += hs[j] * Wlin[(size_t)j * C_ + cls];
        }
        lg[r] = a;
    }

    float mx = fmaxf(fmaxf(lg[0], lg[1]), lg[2]);
    rbuf[tid] = mx;
    __syncthreads();
    for (int s = 128; s > 0; s >>= 1) {
        if (tid < s) rbuf[tid] = fmaxf(rbuf[tid], rbuf[tid + s]);
        __syncthreads();
    }
    mx = rbuf[0];
    __syncthreads();

    float ev[3];
    float es = 0.f;
#pragma unroll
    for (int r = 0; r < 3; ++r) {
        int cls = tid + r * 256;
        if (cls < C_) { ev[r] = expf(lg[r] - mx); es += ev[r]; }
        else ev[r] = 0.f;
    }
    rbuf[tid] = es;
    __syncthreads();
    for (int s = 128; s > 0; s >>= 1) {
        if (tid < s) rbuf[tid] += rbuf[tid + s];
        __syncthreads();
    }
    const float inv = 1.f / rbuf[0];
#pragma unroll
    for (int r = 0; r < 3; ++r) {
        int cls = tid + r * 256;
        if (cls < C_) out[(size_t)b * C_ + cls] = ev[r] * inv;
    }
}

// ---------------------------------------------------------------------------
extern "C" void kernel_launch(void* const* d_in, const int* in_sizes, int n_in,
                              void* d_out, int out_size, void* d_ws, size_t ws_size,
                              hipStream_t stream) {
    const float* seq  = (const float*)d_in[0];
    const float* Wih0 = (const float*)d_in[1];
    const float* Wih  = (const float*)d_in[2];
    const float* Whh  = (const float*)d_in[3];
    const float* bias = (const float*)d_in[4];
    const float* gih  = (const float*)d_in[5];
    const float* bih  = (const float*)d_in[6];
    const float* ghh  = (const float*)d_in[7];
    const float* bhh  = (const float*)d_in[8];
    const float* gc   = (const float*)d_in[9];
    const float* bc   = (const float*)d_in[10];
    const float* Wlin = (const float*)d_in[11];
    const float* blin = (const float*)d_in[12];
    float* out = (float*)d_out;

    // ws: flags 512KB | Hh 8MB | Hl 8MB | Wth 16.8MB | Wtl 16.8MB | Xph | Xpl
    constexpr size_t FLAGRES = 1u << 19;
    constexpr size_t HSZ = (size_t)L_ * HDEP * B_ * H_;   // shorts per H plane
    constexpr size_t XSZ = (size_t)T_ * B_ * XK;
    unsigned* flags = (unsigned*)d_ws;
    short* Hh  = (short*)((char*)d_ws + FLAGRES);
    short* Hl  = Hh + HSZ;
    short* Wth = Hl + HSZ;
    short* Wtl = Wth + (size_t)NMAT2 * MATSZ;
    short* Xph = Wtl + (size_t)NMAT2 * MATSZ;
    short* Xpl = Xph + XSZ;

    hipMemsetAsync(d_ws, 0, FLAGRES + 2 * HSZ * sizeof(short), stream);

    prep_kernel<<<dim3(16, 4, 31), 256, 0, stream>>>(Wih, Whh, Wth, Wtl);
    prep_w0<<<dim3(G4), 256, 0, stream>>>(Wih0, Wth, Wtl);
    prep_x<<<dim3(T_), 256, 0, stream>>>(seq, Xph, Xpl);

    hipFuncSetAttribute((const void*)wave_kernel,
                        hipFuncAttributeMaxDynamicSharedMemorySize, DYNLDS);
    wave_kernel<<<dim3(NBLK), dim3(512), DYNLDS, stream>>>(
        Wth, Wtl, Xph, Xpl, bias, gih, bih, ghh, bhh, gc, bc, Hh, Hl, flags);

    final_kernel<<<B_, 256, 0, stream>>>(Hh, Hl, Wlin, blin, out);
}

// Round 8
// 3899.720 us; speedup vs baseline: 1.5447x; 1.5447x over previous
//
#include <hip/hip_runtime.h>

typedef short s16x8 __attribute__((ext_vector_type(8)));
typedef float f32x4 __attribute__((ext_vector_type(4)));

constexpr int B_  = 128;
constexpr int T_  = 152;
constexpr int I_  = 75;
constexpr int H_  = 256;
constexpr int L_  = 16;
constexpr int C_  = 625;
constexpr int G4  = 1024;          // 4*H
constexpr float EPS_ = 1e-5f;
constexpr int NBLK = 256;          // 16 layers x 16 col-groups
constexpr int ND  = T_ + L_ - 1;   // 167 diagonals
constexpr int NMAT2 = 32;          // 15 W_ih + 16 W_hh + 1 W0^T(padded)
constexpr size_t MATSZ = (size_t)G4 * H_;
constexpr int HDEP = 8;            // H rotation depth (WAR slack 7)

constexpr int WSTRIDE = 266;               // odd dword stride -> <=2-way LDS conflicts
constexpr int WPL_SH  = 64 * WSTRIDE;      // shorts per W plane in LDS (17024)
constexpr int DYNLDS  = 4 * WPL_SH * 2;    // 136192 B dynamic arena
constexpr int FLAGSTR = 32;                // u32 per flag slot (128B line)

__device__ __forceinline__ f32x4 mfma16(s16x8 a, s16x8 b, f32x4 c) {
    return __builtin_amdgcn_mfma_f32_16x16x32_bf16(a, b, c, 0, 0, 0);
}
__device__ __forceinline__ float sigm(float x) { return 1.f / (1.f + expf(-x)); }
__device__ __forceinline__ short f2bf(float x) {
    __bf16 h = (__bf16)x; return __builtin_bit_cast(short, h);
}
__device__ __forceinline__ float bf2f(short s) {
    __bf16 h = __builtin_bit_cast(__bf16, s); return (float)h;
}

// device-coherent 16B load: bypass L1+L2, read at LLC. No buffer_inv needed.
__device__ __forceinline__ s16x8 ldg_dc(const short* p) {
    s16x8 r;
    asm volatile("global_load_dwordx4 %0, %1, off sc0 sc1" : "=v"(r) : "v"(p));
    return r;
}
// wait for all but N outstanding vector-memory ops; ties the 8 buffers so the
// compiler cannot schedule their uses before the wait.
#define VMW(N, a,b,c,d,e,f,g,h)                                              \
    asm volatile("s_waitcnt vmcnt(" N ")"                                    \
                 : "+v"(a), "+v"(b), "+v"(c), "+v"(d),                       \
                   "+v"(e), "+v"(f), "+v"(g), "+v"(h))

__device__ __forceinline__ unsigned* flagp(unsigned* flags, int l, int dd, int g) {
    return flags + (((size_t)l * ND + dd) * 16 + g) * FLAGSTR;
}

// ---------------------------------------------------------------------------
// Prep kernels (transpose + hi/lo bf16 split)
// ---------------------------------------------------------------------------
__global__ void __launch_bounds__(256)
prep_kernel(const float* __restrict__ Wih, const float* __restrict__ Whh,
            short* __restrict__ Wth, short* __restrict__ Wtl) {
    __shared__ float tile[64][65];
    const int mat = blockIdx.z;
    const int n0  = blockIdx.x * 64;
    const int k0  = blockIdx.y * 64;
    const int tid = threadIdx.x;
    const float* src = (mat < 15) ? (Wih + (size_t)mat * MATSZ)
                                  : (Whh + (size_t)(mat - 15) * MATSZ);
#pragma unroll
    for (int r = 0; r < 16; ++r) {
        int idx = r * 256 + tid;
        int kk = idx >> 6, nn = idx & 63;
        tile[kk][nn] = src[(size_t)(k0 + kk) * G4 + n0 + nn];
    }
    __syncthreads();
#pragma unroll
    for (int r = 0; r < 16; ++r) {
        int idx = r * 256 + tid;
        int nn = idx >> 6, kk = idx & 63;
        float w = tile[kk][nn];
        short hi = f2bf(w);
        short lo = f2bf(w - bf2f(hi));
        size_t o = ((size_t)mat * G4 + n0 + nn) * H_ + k0 + kk;
        Wth[o] = hi;
        Wtl[o] = lo;
    }
}

__global__ void __launch_bounds__(256)
prep_w0(const float* __restrict__ Wih0, short* __restrict__ Wth, short* __restrict__ Wtl) {
    const int n = blockIdx.x;
    const int k = threadIdx.x;
    float w = (k < I_) ? Wih0[(size_t)k * G4 + n] : 0.f;
    short hi = f2bf(w);
    short lo = f2bf(w - bf2f(hi));
    size_t o = ((size_t)31 * G4 + n) * H_ + k;
    Wth[o] = hi;
    Wtl[o] = lo;
}

// seq -> Xp[t][row][k], K zero-padded to 256 so layer 0 is branch-uniform.
__global__ void __launch_bounds__(256)
prep_x(const float* __restrict__ seq, short* __restrict__ Xph, short* __restrict__ Xpl) {
    const int t = blockIdx.x;
    for (int idx = threadIdx.x; idx < B_ * H_; idx += 256) {
        int row = idx >> 8, k = idx & 255;
        float v = (k < I_) ? seq[(size_t)row * T_ * I_ + (size_t)t * I_ + k] : 0.f;
        short hi = f2bf(v);
        short lo = f2bf(v - bf2f(hi));
        size_t o = ((size_t)t * B_ + row) * H_ + k;
        Xph[o] = hi;
        Xpl[o] = lo;
    }
}

// BN stats for 8 groups (4 input, 4 recurrent), 4 waves, mt=2 tiles.
__device__ __forceinline__ void bn_stats8(
    const f32x4 aI[2][4], const f32x4 aR[2][4], int tid,
    float (*redS)[4][16], float (*redQ)[4][16],
    float (*mvM)[16], float (*mvI)[16]) {
    const int lane = tid & 63;
    const int wv   = tid >> 6;
    const int lcol = lane & 15;
#pragma unroll
    for (int g = 0; g < 8; ++g) {
        float s = 0.f, q = 0.f;
#pragma unroll
        for (int mt = 0; mt < 2; ++mt) {
            const f32x4& v = (g < 4) ? aI[mt][g] : aR[mt][g - 4];
#pragma unroll
            for (int r = 0; r < 4; ++r) { float a = v[r]; s += a; q += a * a; }
        }
        s += __shfl_xor(s, 16); s += __shfl_xor(s, 32);
        q += __shfl_xor(q, 16); q += __shfl_xor(q, 32);
        if (lane < 16) { redS[g][wv][lcol] = s; redQ[g][wv][lcol] = q; }
    }
    __syncthreads();
    if (tid < 128) {
        int g = tid >> 4, c = tid & 15;
        float s = redS[g][0][c] + redS[g][1][c] + redS[g][2][c] + redS[g][3][c];
        float q = redQ[g][0][c] + redQ[g][1][c] + redQ[g][2][c] + redQ[g][3][c];
        float m = s * (1.0f / B_);
        float v = q * (1.0f / B_) - m * m;
        mvM[g][c] = m;
        mvI[g][c] = rsqrtf(fmaxf(v, 0.f) + EPS_);
    }
    __syncthreads();
}

// ---------------------------------------------------------------------------
// Wavefront kernel: 256 WGs x 256 threads. Persistent W in LDS. Per-producer
// flags (release-store / parallel-lane poll). Device-coherent pipelined H
// loads (no acquire, no buffer_inv).
// ---------------------------------------------------------------------------
__global__ void __launch_bounds__(256, 1)
wave_kernel(const short* __restrict__ Wth, const short* __restrict__ Wtl,
            const short* __restrict__ Xph, const short* __restrict__ Xpl,
            const float* __restrict__ bias,
            const float* __restrict__ g_ih, const float* __restrict__ b_ih,
            const float* __restrict__ g_hh, const float* __restrict__ b_hh,
            const float* __restrict__ g_c,  const float* __restrict__ b_c,
            short* __restrict__ Hh, short* __restrict__ Hl,
            unsigned* __restrict__ flags) {
    extern __shared__ char arena[];
    __shared__ float redS[8][4][16];
    __shared__ float redQ[8][4][16];
    __shared__ float mvM[8][16], mvI[8][16];
    __shared__ float cms[16], cis[16];

    short* Wr_hi = (short*)arena;
    short* Wr_lo = Wr_hi + WPL_SH;
    short* Wi_hi = Wr_lo + WPL_SH;
    short* Wi_lo = Wi_hi + WPL_SH;

    const int b    = blockIdx.x;
    const int l    = ((b & 7) << 1) | ((b >> 3) & 1);  // layers 2x,2x+1 per XCD
    const int gq   = b >> 4;
    const int j0   = gq * 16;
    const int tid  = threadIdx.x;
    const int lane = tid & 63;
    const int wv   = tid >> 6;
    const int quad = lane >> 4;
    const int lcol = lane & 15;
    const int jc   = j0 + lcol;

    float gihv[4], bihv[4], ghhv[4], bhhv[4], bsv[4];
#pragma unroll
    for (int g = 0; g < 4; ++g) {
        int col = l * G4 + g * H_ + jc;
        gihv[g] = g_ih[col];
        bihv[g] = b_ih[col];
        ghhv[g] = g_hh[col];
        bhhv[g] = b_hh[col];
        bsv[g]  = bias[col];
    }
    const float gcv = g_c[l * H_ + jc];
    const float bcv = b_c[l * H_ + jc];

    // ---- persistent weight preload (once) ----
    {
        const int row = tid >> 2, seg = (tid & 3) * 64;
        const int g = row >> 4, c = row & 15;
        const size_t srow = ((size_t)(g * H_ + j0 + c)) * H_ + seg;
        const int miI = (l > 0) ? (l - 1) : 31;
        const short* sWrh = Wth + (size_t)(15 + l) * MATSZ + srow;
        const short* sWrl = Wtl + (size_t)(15 + l) * MATSZ + srow;
        const short* sWih = Wth + (size_t)miI * MATSZ + srow;
        const short* sWil = Wtl + (size_t)miI * MATSZ + srow;
        short* dWrh = Wr_hi + row * WSTRIDE + seg;
        short* dWrl = Wr_lo + row * WSTRIDE + seg;
        short* dWih = Wi_hi + row * WSTRIDE + seg;
        short* dWil = Wi_lo + row * WSTRIDE + seg;
#pragma unroll
        for (int u = 0; u < 8; ++u) {
            *(s16x8*)(dWrh + u * 8) = *(const s16x8*)(sWrh + u * 8);
            *(s16x8*)(dWrl + u * 8) = *(const s16x8*)(sWrl + u * 8);
            *(s16x8*)(dWih + u * 8) = *(const s16x8*)(sWih + u * 8);
            *(s16x8*)(dWil + u * 8) = *(const s16x8*)(sWil + u * 8);
        }
    }
    __syncthreads();

    f32x4 creg[2];
    creg[0] = (f32x4){0.f, 0.f, 0.f, 0.f};
    creg[1] = (f32x4){0.f, 0.f, 0.f, 0.f};

    const int arow0 = wv * 32 + lcol;
    const int koff  = quad * 8;

    for (int t = 0; t < T_; ++t) {
        const int d  = t + l;
        const int pr = (d - 1) & (HDEP - 1);
        const int pw = d & (HDEP - 1);

        // ---- wait: wave 0 lanes poll all prerequisite flags in parallel ----
        if (wv == 0) {
            const int li = lane >> 4, gi = lane & 15;
            unsigned* a = nullptr;
            if (li == 0 && t >= 1)                      a = flagp(flags, l, d - 1, gi);
            else if (li == 1 && l > 0)                  a = flagp(flags, l - 1, d - 1, gi);
            else if (li == 2 && l < 15 && t >= HDEP)    a = flagp(flags, l + 1, d - (HDEP - 1), gi);
            bool done = (a == nullptr);
            while (!__all(done)) {
                if (!done)
                    done = __hip_atomic_load(a, __ATOMIC_RELAXED,
                                             __HIP_MEMORY_SCOPE_AGENT) != 0u;
            }
        }
        __syncthreads();

        // ---- fused K-loop: device-coherent A loads, pipelined 1 ks ahead ----
        f32x4 accI[2][4], accR[2][4];
#pragma unroll
        for (int mt = 0; mt < 2; ++mt)
#pragma unroll
            for (int g = 0; g < 4; ++g) {
                accI[mt][g] = (f32x4){0.f, 0.f, 0.f, 0.f};
                accR[mt][g] = (f32x4){0.f, 0.f, 0.f, 0.f};
            }

        const short* XRh = Hh + (size_t)(l * HDEP + pr) * B_ * H_;
        const short* XRl = Hl + (size_t)(l * HDEP + pr) * B_ * H_;
        const short* XIh = (l > 0) ? (Hh + (size_t)((l - 1) * HDEP + pr) * B_ * H_)
                                   : (Xph + (size_t)t * B_ * H_);
        const short* XIl = (l > 0) ? (Hl + (size_t)((l - 1) * HDEP + pr) * B_ * H_)
                                   : (Xpl + (size_t)t * B_ * H_);

        const short* pRh0 = XRh + (size_t)arow0 * H_ + koff;
        const short* pRh1 = pRh0 + 16 * H_;
        const short* pRl0 = XRl + (size_t)arow0 * H_ + koff;
        const short* pRl1 = pRl0 + 16 * H_;
        const short* pIh0 = XIh + (size_t)arow0 * H_ + koff;
        const short* pIh1 = pIh0 + 16 * H_;
        const short* pIl0 = XIl + (size_t)arow0 * H_ + koff;
        const short* pIl1 = pIl0 + 16 * H_;

        s16x8 cRh0 = ldg_dc(pRh0), cRh1 = ldg_dc(pRh1);
        s16x8 cRl0 = ldg_dc(pRl0), cRl1 = ldg_dc(pRl1);
        s16x8 cIh0 = ldg_dc(pIh0), cIh1 = ldg_dc(pIh1);
        s16x8 cIl0 = ldg_dc(pIl0), cIl1 = ldg_dc(pIl1);

#pragma unroll
        for (int ks = 0; ks < 8; ++ks) {
            s16x8 nRh0, nRh1, nRl0, nRl1, nIh0, nIh1, nIl0, nIl1;
            if (ks < 7) {
                const int ko = (ks + 1) * 32;
                nRh0 = ldg_dc(pRh0 + ko); nRh1 = ldg_dc(pRh1 + ko);
                nRl0 = ldg_dc(pRl0 + ko); nRl1 = ldg_dc(pRl1 + ko);
                nIh0 = ldg_dc(pIh0 + ko); nIh1 = ldg_dc(pIh1 + ko);
                nIl0 = ldg_dc(pIl0 + ko); nIl1 = ldg_dc(pIl1 + ko);
                VMW("8", cRh0, cRh1, cRl0, cRl1, cIh0, cIh1, cIl0, cIl1);
            } else {
                VMW("0", cRh0, cRh1, cRl0, cRl1, cIh0, cIh1, cIl0, cIl1);
            }
#pragma unroll
            for (int g = 0; g < 4; ++g) {
                const int bo = (g * 16 + lcol) * WSTRIDE + ks * 32 + koff;
                s16x8 brh = *(const s16x8*)&Wr_hi[bo];
                s16x8 brl = *(const s16x8*)&Wr_lo[bo];
                s16x8 bih = *(const s16x8*)&Wi_hi[bo];
                s16x8 bil = *(const s16x8*)&Wi_lo[bo];
                accR[0][g] = mfma16(cRh0, brh, accR[0][g]);
                accR[0][g] = mfma16(cRl0, brh, accR[0][g]);
                accR[0][g] = mfma16(cRh0, brl, accR[0][g]);
                accR[0][g] = mfma16(cRl0, brl, accR[0][g]);
                accR[1][g] = mfma16(cRh1, brh, accR[1][g]);
                accR[1][g] = mfma16(cRl1, brh, accR[1][g]);
                accR[1][g] = mfma16(cRh1, brl, accR[1][g]);
                accR[1][g] = mfma16(cRl1, brl, accR[1][g]);
                accI[0][g] = mfma16(cIh0, bih, accI[0][g]);
                accI[0][g] = mfma16(cIl0, bih, accI[0][g]);
                accI[0][g] = mfma16(cIh0, bil, accI[0][g]);
                accI[0][g] = mfma16(cIl0, bil, accI[0][g]);
                accI[1][g] = mfma16(cIh1, bih, accI[1][g]);
                accI[1][g] = mfma16(cIl1, bih, accI[1][g]);
                accI[1][g] = mfma16(cIh1, bil, accI[1][g]);
                accI[1][g] = mfma16(cIl1, bil, accI[1][g]);
            }
            if (ks < 7) {
                cRh0 = nRh0; cRh1 = nRh1; cRl0 = nRl0; cRl1 = nRl1;
                cIh0 = nIh0; cIh1 = nIh1; cIl0 = nIl0; cIl1 = nIl1;
            }
        }

        // ---- BN stats (both GEMMs, one pass) ----
        bn_stats8(accI, accR, tid, redS, redQ, mvM, mvI);

        f32x4 osv[2];
#pragma unroll
        for (int mt = 0; mt < 2; ++mt) {
#pragma unroll
            for (int r = 0; r < 4; ++r) {
                float bn0 = (accI[mt][0][r] - mvM[0][lcol]) * mvI[0][lcol] * gihv[0] + bihv[0];
                float bn1 = (accI[mt][1][r] - mvM[1][lcol]) * mvI[1][lcol] * gihv[1] + bihv[1];
                float bn2 = (accI[mt][2][r] - mvM[2][lcol]) * mvI[2][lcol] * gihv[2] + bihv[2];
                float bn3 = (accI[mt][3][r] - mvM[3][lcol]) * mvI[3][lcol] * gihv[3] + bihv[3];
                float sf = (accR[mt][0][r] - mvM[4][lcol]) * mvI[4][lcol] * ghhv[0] + bhhv[0] + bn0 + bsv[0];
                float si = (accR[mt][1][r] - mvM[5][lcol]) * mvI[5][lcol] * ghhv[1] + bhhv[1] + bn1 + bsv[1];
                float so = (accR[mt][2][r] - mvM[6][lcol]) * mvI[6][lcol] * ghhv[2] + bhhv[2] + bn2 + bsv[2];
                float sg = (accR[mt][3][r] - mvM[7][lcol]) * mvI[7][lcol] * ghhv[3] + bhhv[3] + bn3 + bsv[3];
                creg[mt][r] = sigm(sf) * creg[mt][r] + sigm(si) * tanhf(sg);
                osv[mt][r]  = so;
            }
        }

        // ---- BN over c ----
        {
            float s = 0.f, q = 0.f;
#pragma unroll
            for (int mt = 0; mt < 2; ++mt)
#pragma unroll
                for (int r = 0; r < 4; ++r) { float a = creg[mt][r]; s += a; q += a * a; }
            s += __shfl_xor(s, 16); s += __shfl_xor(s, 32);
            q += __shfl_xor(q, 16); q += __shfl_xor(q, 32);
            if (lane < 16) { redS[0][wv][lcol] = s; redQ[0][wv][lcol] = q; }
        }
        __syncthreads();
        if (tid < 16) {
            float s = redS[0][0][tid] + redS[0][1][tid] + redS[0][2][tid] + redS[0][3][tid];
            float q = redQ[0][0][tid] + redQ[0][1][tid] + redQ[0][2][tid] + redQ[0][3][tid];
            float m = s * (1.0f / B_);
            float v = q * (1.0f / B_) - m * m;
            cms[tid] = m;
            cis[tid] = rsqrtf(fmaxf(v, 0.f) + EPS_);
        }
        __syncthreads();
        {
            const float m = cms[lcol], is = cis[lcol];
            short* Hwh = Hh + (size_t)(l * HDEP + pw) * B_ * H_;
            short* Hwl = Hl + (size_t)(l * HDEP + pw) * B_ * H_;
#pragma unroll
            for (int mt = 0; mt < 2; ++mt)
#pragma unroll
                for (int r = 0; r < 4; ++r) {
                    int row = wv * 32 + mt * 16 + quad * 4 + r;
                    float hv = sigm(osv[mt][r]) * tanhf((creg[mt][r] - m) * is * gcv + bcv);
                    short hi = f2bf(hv);
                    short lo = f2bf(hv - bf2f(hi));
                    __hip_atomic_store(&Hwh[(size_t)row * H_ + jc], hi,
                                       __ATOMIC_RELAXED, __HIP_MEMORY_SCOPE_AGENT);
                    __hip_atomic_store(&Hwl[(size_t)row * H_ + jc], lo,
                                       __ATOMIC_RELAXED, __HIP_MEMORY_SCOPE_AGENT);
                }
        }
        __syncthreads();   // compiler drains vmcnt in every wave before barrier
        if (tid == 0)
            __hip_atomic_store(flagp(flags, l, d, gq), 1u,
                               __ATOMIC_RELEASE, __HIP_MEMORY_SCOPE_AGENT);
    }
}

// ---------------------------------------------------------------------------
// Final linear + softmax: one WG per batch row.
// ---------------------------------------------------------------------------
__global__ void __launch_bounds__(256)
final_kernel(const short* __restrict__ Hh, const short* __restrict__ Hl,
             const float* __restrict__ Wlin, const float* __restrict__ blin,
             float* __restrict__ out) {
    const int b   = blockIdx.x;
    const int tid = threadIdx.x;
    __shared__ float hs[H_];
    __shared__ float rbuf[256];
    constexpr int lastPar = (ND - 1) & (HDEP - 1);  // = 6

    {
        size_t o = (size_t)((L_ - 1) * HDEP + lastPar) * B_ * H_ + (size_t)b * H_ + tid;
        hs[tid] = bf2f(Hh[o]) + bf2f(Hl[o]);
    }
    __syncthreads();

    float lg[3];
#pragma unroll
    for (int r = 0; r < 3; ++r) {
        int cls = tid + r * 256;
        float a = -1e30f;
        if (cls < C_) {
            a = blin[cls];
            for (int j = 0; j < H_; ++j) a += hs[j] * Wlin[(size_t)j * C_ + cls];
        }
        lg[r] = a;
    }

    float mx = fmaxf(fmaxf(lg[0], lg[1]), lg[2]);
    rbuf[tid] = mx;
    __syncthreads();
    for (int s = 128; s > 0; s >>= 1) {
        if (tid < s) rbuf[tid] = fmaxf(rbuf[tid], rbuf[tid + s]);
        __syncthreads();
    }
    mx = rbuf[0];
    __syncthreads();

    float ev[3];
    float es = 0.f;
#pragma unroll
    for (int r = 0; r < 3; ++r) {
        int cls = tid + r * 256;
        if (cls < C_) { ev[r] = expf(lg[r] - mx); es += ev[r]; }
        else ev[r] = 0.f;
    }
    rbuf[tid] = es;
    __syncthreads();
    for (int s = 128; s > 0; s >>= 1) {
        if (tid < s) rbuf[tid] += rbuf[tid + s];
        __syncthreads();
    }
    const float inv = 1.f / rbuf[0];
#pragma unroll
    for (int r = 0; r < 3; ++r) {
        int cls = tid + r * 256;
        if (cls < C_) out[(size_t)b * C_ + cls] = ev[r] * inv;
    }
}

// ---------------------------------------------------------------------------
extern "C" void kernel_launch(void* const* d_in, const int* in_sizes, int n_in,
                              void* d_out, int out_size, void* d_ws, size_t ws_size,
                              hipStream_t stream) {
    const float* seq  = (const float*)d_in[0];
    const float* Wih0 = (const float*)d_in[1];
    const float* Wih  = (const float*)d_in[2];
    const float* Whh  = (const float*)d_in[3];
    const float* bias = (const float*)d_in[4];
    const float* gih  = (const float*)d_in[5];
    const float* bih  = (const float*)d_in[6];
    const float* ghh  = (const float*)d_in[7];
    const float* bhh  = (const float*)d_in[8];
    const float* gc   = (const float*)d_in[9];
    const float* bc   = (const float*)d_in[10];
    const float* Wlin = (const float*)d_in[11];
    const float* blin = (const float*)d_in[12];
    float* out = (float*)d_out;

    // ws: flags 8MB | Hh 8MB | Hl 8MB | Wth 16.8MB | Wtl 16.8MB | Xph 10MB | Xpl 10MB
    constexpr size_t FLAGRES = 1u << 23;
    constexpr size_t HSZ = (size_t)L_ * HDEP * B_ * H_;   // shorts per H plane
    constexpr size_t XSZ = (size_t)T_ * B_ * H_;          // shorts per Xp plane
    unsigned* flags = (unsigned*)d_ws;
    short* Hh  = (short*)((char*)d_ws + FLAGRES);
    short* Hl  = Hh + HSZ;
    short* Wth = Hl + HSZ;
    short* Wtl = Wth + (size_t)NMAT2 * MATSZ;
    short* Xph = Wtl + (size_t)NMAT2 * MATSZ;
    short* Xpl = Xph + XSZ;

    hipMemsetAsync(d_ws, 0, FLAGRES + 2 * HSZ * sizeof(short), stream);

    prep_kernel<<<dim3(16, 4, 31), 256, 0, stream>>>(Wih, Whh, Wth, Wtl);
    prep_w0<<<dim3(G4), 256, 0, stream>>>(Wih0, Wth, Wtl);
    prep_x<<<dim3(T_), 256, 0, stream>>>(seq, Xph, Xpl);

    hipFuncSetAttribute((const void*)wave_kernel,
                        hipFuncAttributeMaxDynamicSharedMemorySize, DYNLDS);
    wave_kernel<<<dim3(NBLK), dim3(256), DYNLDS, stream>>>(
        Wth, Wtl, Xph, Xpl, bias, gih, bih, ghh, bhh, gc, bc, Hh, Hl, flags);

    final_kernel<<<B_, 256, 0, stream>>>(Hh, Hl, Wlin, blin, out);
}

// Round 9
// 3735.308 us; speedup vs baseline: 1.6127x; 1.0440x over previous
//
#include <hip/hip_runtime.h>

typedef short s16x8 __attribute__((ext_vector_type(8)));
typedef float f32x4 __attribute__((ext_vector_type(4)));

constexpr int B_  = 128;
constexpr int T_  = 152;
constexpr int I_  = 75;
constexpr int H_  = 256;
constexpr int L_  = 16;
constexpr int C_  = 625;
constexpr int G4  = 1024;          // 4*H
constexpr float EPS_ = 1e-5f;
constexpr int NBLK = 256;          // 16 layers x 16 col-groups
constexpr int ND  = T_ + L_ - 1;   // 167 diagonals
constexpr int NMAT2 = 32;          // 15 W_ih + 16 W_hh + 1 W0^T(padded)
constexpr size_t MATSZ = (size_t)G4 * H_;
constexpr int HDEP = 8;            // H rotation depth (WAR slack 7)

constexpr int WSTRIDE = 266;               // odd dword stride -> <=2-way LDS conflicts
constexpr int WPL_SH  = 64 * WSTRIDE;      // shorts per W plane in LDS (17024)
constexpr int DYNLDS  = 4 * WPL_SH * 2;    // 136192 B dynamic arena

__device__ __forceinline__ f32x4 mfma16(s16x8 a, s16x8 b, f32x4 c) {
    return __builtin_amdgcn_mfma_f32_16x16x32_bf16(a, b, c, 0, 0, 0);
}
__device__ __forceinline__ float sigm(float x) { return 1.f / (1.f + expf(-x)); }
__device__ __forceinline__ short f2bf(float x) {
    __bf16 h = (__bf16)x; return __builtin_bit_cast(short, h);
}
__device__ __forceinline__ float bf2f(short s) {
    __bf16 h = __builtin_bit_cast(__bf16, s); return (float)h;
}

// device-coherent 16B load: bypass L1+L2, read at LLC.
__device__ __forceinline__ s16x8 ldg_dc(const short* p) {
    s16x8 r;
    asm volatile("global_load_dwordx4 %0, %1, off sc0 sc1" : "=v"(r) : "v"(p));
    return r;
}
__device__ __forceinline__ void stg_dc16(short* p, short v) {
    asm volatile("global_store_short %0, %1, off sc0 sc1" :: "v"(p), "v"(v));
}
__device__ __forceinline__ unsigned ldf_dc(const unsigned* p) {
    unsigned v;
    asm volatile("global_load_dword %0, %1, off sc0 sc1\n\ts_waitcnt vmcnt(0)"
                 : "=v"(v) : "v"(p));
    return v;
}
// wait for all but N outstanding vector-memory ops; ties the 8 buffers.
#define VMW(N, a,b,c,d,e,f,g,h)                                              \
    asm volatile("s_waitcnt vmcnt(" N ")"                                    \
                 : "+v"(a), "+v"(b), "+v"(c), "+v"(d),                       \
                   "+v"(e), "+v"(f), "+v"(g), "+v"(h))

// one 128B line (32 dwords) per (layer, diagonal); word g = producer gq's flag
__device__ __forceinline__ unsigned* flagline(unsigned* flags, int l, int dd) {
    return flags + (size_t)(l * ND + dd) * 32;
}

// ---------------------------------------------------------------------------
// Prep kernels (transpose + hi/lo bf16 split)
// ---------------------------------------------------------------------------
__global__ void __launch_bounds__(256)
prep_kernel(const float* __restrict__ Wih, const float* __restrict__ Whh,
            short* __restrict__ Wth, short* __restrict__ Wtl) {
    __shared__ float tile[64][65];
    const int mat = blockIdx.z;
    const int n0  = blockIdx.x * 64;
    const int k0  = blockIdx.y * 64;
    const int tid = threadIdx.x;
    const float* src = (mat < 15) ? (Wih + (size_t)mat * MATSZ)
                                  : (Whh + (size_t)(mat - 15) * MATSZ);
#pragma unroll
    for (int r = 0; r < 16; ++r) {
        int idx = r * 256 + tid;
        int kk = idx >> 6, nn = idx & 63;
        tile[kk][nn] = src[(size_t)(k0 + kk) * G4 + n0 + nn];
    }
    __syncthreads();
#pragma unroll
    for (int r = 0; r < 16; ++r) {
        int idx = r * 256 + tid;
        int nn = idx >> 6, kk = idx & 63;
        float w = tile[kk][nn];
        short hi = f2bf(w);
        short lo = f2bf(w - bf2f(hi));
        size_t o = ((size_t)mat * G4 + n0 + nn) * H_ + k0 + kk;
        Wth[o] = hi;
        Wtl[o] = lo;
    }
}

__global__ void __launch_bounds__(256)
prep_w0(const float* __restrict__ Wih0, short* __restrict__ Wth, short* __restrict__ Wtl) {
    const int n = blockIdx.x;
    const int k = threadIdx.x;
    float w = (k < I_) ? Wih0[(size_t)k * G4 + n] : 0.f;
    short hi = f2bf(w);
    short lo = f2bf(w - bf2f(hi));
    size_t o = ((size_t)31 * G4 + n) * H_ + k;
    Wth[o] = hi;
    Wtl[o] = lo;
}

// seq -> Xp[t][row][k], K zero-padded to 256 so layer 0 is branch-uniform.
__global__ void __launch_bounds__(256)
prep_x(const float* __restrict__ seq, short* __restrict__ Xph, short* __restrict__ Xpl) {
    const int t = blockIdx.x;
    for (int idx = threadIdx.x; idx < B_ * H_; idx += 256) {
        int row = idx >> 8, k = idx & 255;
        float v = (k < I_) ? seq[(size_t)row * T_ * I_ + (size_t)t * I_ + k] : 0.f;
        short hi = f2bf(v);
        short lo = f2bf(v - bf2f(hi));
        size_t o = ((size_t)t * B_ + row) * H_ + k;
        Xph[o] = hi;
        Xpl[o] = lo;
    }
}

// BN stats for 8 groups (4 input, 4 recurrent), 4 waves, mt=2 tiles.
__device__ __forceinline__ void bn_stats8(
    const f32x4 aI[2][4], const f32x4 aR[2][4], int tid,
    float (*redS)[4][16], float (*redQ)[4][16],
    float (*mvM)[16], float (*mvI)[16]) {
    const int lane = tid & 63;
    const int wv   = tid >> 6;
    const int lcol = lane & 15;
#pragma unroll
    for (int g = 0; g < 8; ++g) {
        float s = 0.f, q = 0.f;
#pragma unroll
        for (int mt = 0; mt < 2; ++mt) {
            const f32x4& v = (g < 4) ? aI[mt][g] : aR[mt][g - 4];
#pragma unroll
            for (int r = 0; r < 4; ++r) { float a = v[r]; s += a; q += a * a; }
        }
        s += __shfl_xor(s, 16); s += __shfl_xor(s, 32);
        q += __shfl_xor(q, 16); q += __shfl_xor(q, 32);
        if (lane < 16) { redS[g][wv][lcol] = s; redQ[g][wv][lcol] = q; }
    }
    __syncthreads();
    if (tid < 128) {
        int g = tid >> 4, c = tid & 15;
        float s = redS[g][0][c] + redS[g][1][c] + redS[g][2][c] + redS[g][3][c];
        float q = redQ[g][0][c] + redQ[g][1][c] + redQ[g][2][c] + redQ[g][3][c];
        float m = s * (1.0f / B_);
        float v = q * (1.0f / B_) - m * m;
        mvM[g][c] = m;
        mvI[g][c] = rsqrtf(fmaxf(v, 0.f) + EPS_);
    }
    __syncthreads();
}

// ---------------------------------------------------------------------------
// Wavefront kernel: 256 WGs x 256 threads. Persistent W in LDS. Packed-line
// flags (1 line per (l,d)), raw sc0sc1 store/poll with s_sleep backoff,
// all-wave independent polling (no post-poll barrier). DC pipelined A loads.
// ---------------------------------------------------------------------------
__global__ void __launch_bounds__(256, 1)
wave_kernel(const short* __restrict__ Wth, const short* __restrict__ Wtl,
            const short* __restrict__ Xph, const short* __restrict__ Xpl,
            const float* __restrict__ bias,
            const float* __restrict__ g_ih, const float* __restrict__ b_ih,
            const float* __restrict__ g_hh, const float* __restrict__ b_hh,
            const float* __restrict__ g_c,  const float* __restrict__ b_c,
            short* __restrict__ Hh, short* __restrict__ Hl,
            unsigned* __restrict__ flags) {
    extern __shared__ char arena[];
    __shared__ float redS[8][4][16];
    __shared__ float redQ[8][4][16];
    __shared__ float mvM[8][16], mvI[8][16];
    __shared__ float cms[16], cis[16];

    short* Wr_hi = (short*)arena;
    short* Wr_lo = Wr_hi + WPL_SH;
    short* Wi_hi = Wr_lo + WPL_SH;
    short* Wi_lo = Wi_hi + WPL_SH;

    const int b    = blockIdx.x;
    const int l    = ((b & 7) << 1) | ((b >> 3) & 1);  // layers 2x,2x+1 per XCD
    const int gq   = b >> 4;
    const int j0   = gq * 16;
    const int tid  = threadIdx.x;
    const int lane = tid & 63;
    const int wv   = tid >> 6;
    const int quad = lane >> 4;
    const int lcol = lane & 15;
    const int jc   = j0 + lcol;

    float gihv[4], bihv[4], ghhv[4], bhhv[4], bsv[4];
#pragma unroll
    for (int g = 0; g < 4; ++g) {
        int col = l * G4 + g * H_ + jc;
        gihv[g] = g_ih[col];
        bihv[g] = b_ih[col];
        ghhv[g] = g_hh[col];
        bhhv[g] = b_hh[col];
        bsv[g]  = bias[col];
    }
    const float gcv = g_c[l * H_ + jc];
    const float bcv = b_c[l * H_ + jc];

    // ---- persistent weight preload (once) ----
    {
        const int row = tid >> 2, seg = (tid & 3) * 64;
        const int g = row >> 4, c = row & 15;
        const size_t srow = ((size_t)(g * H_ + j0 + c)) * H_ + seg;
        const int miI = (l > 0) ? (l - 1) : 31;
        const short* sWrh = Wth + (size_t)(15 + l) * MATSZ + srow;
        const short* sWrl = Wtl + (size_t)(15 + l) * MATSZ + srow;
        const short* sWih = Wth + (size_t)miI * MATSZ + srow;
        const short* sWil = Wtl + (size_t)miI * MATSZ + srow;
        short* dWrh = Wr_hi + row * WSTRIDE + seg;
        short* dWrl = Wr_lo + row * WSTRIDE + seg;
        short* dWih = Wi_hi + row * WSTRIDE + seg;
        short* dWil = Wi_lo + row * WSTRIDE + seg;
#pragma unroll
        for (int u = 0; u < 8; ++u) {
            *(s16x8*)(dWrh + u * 8) = *(const s16x8*)(sWrh + u * 8);
            *(s16x8*)(dWrl + u * 8) = *(const s16x8*)(sWrl + u * 8);
            *(s16x8*)(dWih + u * 8) = *(const s16x8*)(sWih + u * 8);
            *(s16x8*)(dWil + u * 8) = *(const s16x8*)(sWil + u * 8);
        }
    }
    __syncthreads();

    f32x4 creg[2];
    creg[0] = (f32x4){0.f, 0.f, 0.f, 0.f};
    creg[1] = (f32x4){0.f, 0.f, 0.f, 0.f};

    const int arow0 = wv * 32 + lcol;
    const int koff  = quad * 8;

    for (int t = 0; t < T_; ++t) {
        const int d  = t + l;
        const int pr = (d - 1) & (HDEP - 1);
        const int pw = d & (HDEP - 1);

        // ---- wait: every wave polls; lanes 0-15:fO, 16-31:fB, 32-47:fW.
        //      One 128B line per dependency per round + s_sleep backoff. ----
        {
            const int li = lane >> 4, gi = lane & 15;
            const unsigned* a = nullptr;
            if (li == 0 && t >= 1)                   a = flagline(flags, l, d - 1) + gi;
            else if (li == 1 && l > 0)               a = flagline(flags, l - 1, d - 1) + gi;
            else if (li == 2 && l < 15 && t >= HDEP) a = flagline(flags, l + 1, d - (HDEP - 1)) + gi;
            bool done = (a == nullptr);
            if (!done) done = (ldf_dc(a) != 0u);
            while (!__all(done)) {
                __builtin_amdgcn_s_sleep(2);
                if (!done) done = (ldf_dc(a) != 0u);
            }
        }

        // ---- fused K-loop: device-coherent A loads, pipelined 1 ks ahead ----
        f32x4 accI[2][4], accR[2][4];
#pragma unroll
        for (int mt = 0; mt < 2; ++mt)
#pragma unroll
            for (int g = 0; g < 4; ++g) {
                accI[mt][g] = (f32x4){0.f, 0.f, 0.f, 0.f};
                accR[mt][g] = (f32x4){0.f, 0.f, 0.f, 0.f};
            }

        const short* XRh = Hh + (size_t)(l * HDEP + pr) * B_ * H_;
        const short* XRl = Hl + (size_t)(l * HDEP + pr) * B_ * H_;
        const short* XIh = (l > 0) ? (Hh + (size_t)((l - 1) * HDEP + pr) * B_ * H_)
                                   : (Xph + (size_t)t * B_ * H_);
        const short* XIl = (l > 0) ? (Hl + (size_t)((l - 1) * HDEP + pr) * B_ * H_)
                                   : (Xpl + (size_t)t * B_ * H_);

        const short* pRh0 = XRh + (size_t)arow0 * H_ + koff;
        const short* pRh1 = pRh0 + 16 * H_;
        const short* pRl0 = XRl + (size_t)arow0 * H_ + koff;
        const short* pRl1 = pRl0 + 16 * H_;
        const short* pIh0 = XIh + (size_t)arow0 * H_ + koff;
        const short* pIh1 = pIh0 + 16 * H_;
        const short* pIl0 = XIl + (size_t)arow0 * H_ + koff;
        const short* pIl1 = pIl0 + 16 * H_;

        s16x8 cRh0 = ldg_dc(pRh0), cRh1 = ldg_dc(pRh1);
        s16x8 cRl0 = ldg_dc(pRl0), cRl1 = ldg_dc(pRl1);
        s16x8 cIh0 = ldg_dc(pIh0), cIh1 = ldg_dc(pIh1);
        s16x8 cIl0 = ldg_dc(pIl0), cIl1 = ldg_dc(pIl1);

#pragma unroll
        for (int ks = 0; ks < 8; ++ks) {
            s16x8 nRh0, nRh1, nRl0, nRl1, nIh0, nIh1, nIl0, nIl1;
            if (ks < 7) {
                const int ko = (ks + 1) * 32;
                nRh0 = ldg_dc(pRh0 + ko); nRh1 = ldg_dc(pRh1 + ko);
                nRl0 = ldg_dc(pRl0 + ko); nRl1 = ldg_dc(pRl1 + ko);
                nIh0 = ldg_dc(pIh0 + ko); nIh1 = ldg_dc(pIh1 + ko);
                nIl0 = ldg_dc(pIl0 + ko); nIl1 = ldg_dc(pIl1 + ko);
                VMW("8", cRh0, cRh1, cRl0, cRl1, cIh0, cIh1, cIl0, cIl1);
            } else {
                VMW("0", cRh0, cRh1, cRl0, cRl1, cIh0, cIh1, cIl0, cIl1);
            }
#pragma unroll
            for (int g = 0; g < 4; ++g) {
                const int bo = (g * 16 + lcol) * WSTRIDE + ks * 32 + koff;
                s16x8 brh = *(const s16x8*)&Wr_hi[bo];
                s16x8 brl = *(const s16x8*)&Wr_lo[bo];
                s16x8 bih = *(const s16x8*)&Wi_hi[bo];
                s16x8 bil = *(const s16x8*)&Wi_lo[bo];
                accR[0][g] = mfma16(cRh0, brh, accR[0][g]);
                accR[0][g] = mfma16(cRl0, brh, accR[0][g]);
                accR[0][g] = mfma16(cRh0, brl, accR[0][g]);
                accR[0][g] = mfma16(cRl0, brl, accR[0][g]);
                accR[1][g] = mfma16(cRh1, brh, accR[1][g]);
                accR[1][g] = mfma16(cRl1, brh, accR[1][g]);
                accR[1][g] = mfma16(cRh1, brl, accR[1][g]);
                accR[1][g] = mfma16(cRl1, brl, accR[1][g]);
                accI[0][g] = mfma16(cIh0, bih, accI[0][g]);
                accI[0][g] = mfma16(cIl0, bih, accI[0][g]);
                accI[0][g] = mfma16(cIh0, bil, accI[0][g]);
                accI[0][g] = mfma16(cIl0, bil, accI[0][g]);
                accI[1][g] = mfma16(cIh1, bih, accI[1][g]);
                accI[1][g] = mfma16(cIl1, bih, accI[1][g]);
                accI[1][g] = mfma16(cIh1, bil, accI[1][g]);
                accI[1][g] = mfma16(cIl1, bil, accI[1][g]);
            }
            if (ks < 7) {
                cRh0 = nRh0; cRh1 = nRh1; cRl0 = nRl0; cRl1 = nRl1;
                cIh0 = nIh0; cIh1 = nIh1; cIl0 = nIl0; cIl1 = nIl1;
            }
        }

        // ---- BN stats (both GEMMs, one pass) ----
        bn_stats8(accI, accR, tid, redS, redQ, mvM, mvI);

        f32x4 osv[2];
#pragma unroll
        for (int mt = 0; mt < 2; ++mt) {
#pragma unroll
            for (int r = 0; r < 4; ++r) {
                float bn0 = (accI[mt][0][r] - mvM[0][lcol]) * mvI[0][lcol] * gihv[0] + bihv[0];
                float bn1 = (accI[mt][1][r] - mvM[1][lcol]) * mvI[1][lcol] * gihv[1] + bihv[1];
                float bn2 = (accI[mt][2][r] - mvM[2][lcol]) * mvI[2][lcol] * gihv[2] + bihv[2];
                float bn3 = (accI[mt][3][r] - mvM[3][lcol]) * mvI[3][lcol] * gihv[3] + bihv[3];
                float sf = (accR[mt][0][r] - mvM[4][lcol]) * mvI[4][lcol] * ghhv[0] + bhhv[0] + bn0 + bsv[0];
                float si = (accR[mt][1][r] - mvM[5][lcol]) * mvI[5][lcol] * ghhv[1] + bhhv[1] + bn1 + bsv[1];
                float so = (accR[mt][2][r] - mvM[6][lcol]) * mvI[6][lcol] * ghhv[2] + bhhv[2] + bn2 + bsv[2];
                float sg = (accR[mt][3][r] - mvM[7][lcol]) * mvI[7][lcol] * ghhv[3] + bhhv[3] + bn3 + bsv[3];
                creg[mt][r] = sigm(sf) * creg[mt][r] + sigm(si) * tanhf(sg);
                osv[mt][r]  = so;
            }
        }

        // ---- BN over c ----
        {
            float s = 0.f, q = 0.f;
#pragma unroll
            for (int mt = 0; mt < 2; ++mt)
#pragma unroll
                for (int r = 0; r < 4; ++r) { float a = creg[mt][r]; s += a; q += a * a; }
            s += __shfl_xor(s, 16); s += __shfl_xor(s, 32);
            q += __shfl_xor(q, 16); q += __shfl_xor(q, 32);
            if (lane < 16) { redS[0][wv][lcol] = s; redQ[0][wv][lcol] = q; }
        }
        __syncthreads();
        if (tid < 16) {
            float s = redS[0][0][tid] + redS[0][1][tid] + redS[0][2][tid] + redS[0][3][tid];
            float q = redQ[0][0][tid] + redQ[0][1][tid] + redQ[0][2][tid] + redQ[0][3][tid];
            float m = s * (1.0f / B_);
            float v = q * (1.0f / B_) - m * m;
            cms[tid] = m;
            cis[tid] = rsqrtf(fmaxf(v, 0.f) + EPS_);
        }
        __syncthreads();
        {
            const float m = cms[lcol], is = cis[lcol];
            short* Hwh = Hh + (size_t)(l * HDEP + pw) * B_ * H_;
            short* Hwl = Hl + (size_t)(l * HDEP + pw) * B_ * H_;
#pragma unroll
            for (int mt = 0; mt < 2; ++mt)
#pragma unroll
                for (int r = 0; r < 4; ++r) {
                    int row = wv * 32 + mt * 16 + quad * 4 + r;
                    float hv = sigm(osv[mt][r]) * tanhf((creg[mt][r] - m) * is * gcv + bcv);
                    short hi = f2bf(hv);
                    short lo = f2bf(hv - bf2f(hi));
                    stg_dc16(&Hwh[(size_t)row * H_ + jc], hi);
                    stg_dc16(&Hwl[(size_t)row * H_ + jc], lo);
                }
        }
        __syncthreads();   // every wave drains vmcnt before barrier -> H at LLC
        if (tid == 0) {
            unsigned* p = flagline(flags, l, d) + gq;
            asm volatile("global_store_dword %0, %1, off sc0 sc1"
                         :: "v"(p), "v"(1u) : "memory");
        }
    }
}

// ---------------------------------------------------------------------------
// Final linear + softmax: one WG per batch row.
// ---------------------------------------------------------------------------
__global__ void __launch_bounds__(256)
final_kernel(const short* __restrict__ Hh, const short* __restrict__ Hl,
             const float* __restrict__ Wlin, const float* __restrict__ blin,
             float* __restrict__ out) {
    const int b   = blockIdx.x;
    const int tid = threadIdx.x;
    __shared__ float hs[H_];
    __shared__ float rbuf[256];
    constexpr int lastPar = (ND - 1) & (HDEP - 1);  // = 6

    {
        size_t o = (size_t)((L_ - 1) * HDEP + lastPar) * B_ * H_ + (size_t)b * H_ + tid;
        hs[tid] = bf2f(Hh[o]) + bf2f(Hl[o]);
    }
    __syncthreads();

    float lg[3];
#pragma unroll
    for (int r = 0; r < 3; ++r) {
        int cls = tid + r * 256;
        float a = -1e30f;
        if (cls < C_) {
            a = blin[cls];
            for (int j = 0; j < H_; ++j) a += hs[j] * Wlin[(size_t)j * C_ + cls];
        }
        lg[r] = a;
    }

    float mx = fmaxf(fmaxf(lg[0], lg[1]), lg[2]);
    rbuf[tid] = mx;
    __syncthreads();
    for (int s = 128; s > 0; s >>= 1) {
        if (tid < s) rbuf[tid] = fmaxf(rbuf[tid], rbuf[tid + s]);
        __syncthreads();
    }
    mx = rbuf[0];
    __syncthreads();

    float ev[3];
    float es = 0.f;
#pragma unroll
    for (int r = 0; r < 3; ++r) {
        int cls = tid + r * 256;
        if (cls < C_) { ev[r] = expf(lg[r] - mx); es += ev[r]; }
        else ev[r] = 0.f;
    }
    rbuf[tid] = es;
    __syncthreads();
    for (int s = 128; s > 0; s >>= 1) {
        if (tid < s) rbuf[tid] += rbuf[tid + s];
        __syncthreads();
    }
    const float inv = 1.f / rbuf[0];
#pragma unroll
    for (int r = 0; r < 3; ++r) {
        int cls = tid + r * 256;
        if (cls < C_) out[(size_t)b * C_ + cls] = ev[r] * inv;
    }
}

// ---------------------------------------------------------------------------
extern "C" void kernel_launch(void* const* d_in, const int* in_sizes, int n_in,
                              void* d_out, int out_size, void* d_ws, size_t ws_size,
                              hipStream_t stream) {
    const float* seq  = (const float*)d_in[0];
    const float* Wih0 = (const float*)d_in[1];
    const float* Wih  = (const float*)d_in[2];
    const float* Whh  = (const float*)d_in[3];
    const float* bias = (const float*)d_in[4];
    const float* gih  = (const float*)d_in[5];
    const float* bih  = (const float*)d_in[6];
    const float* ghh  = (const float*)d_in[7];
    const float* bhh  = (const float*)d_in[8];
    const float* gc   = (const float*)d_in[9];
    const float* bc   = (const float*)d_in[10];
    const float* Wlin = (const float*)d_in[11];
    const float* blin = (const float*)d_in[12];
    float* out = (float*)d_out;

    // ws: flags 1MB | Hh 8MB | Hl 8MB | Wth 16.8MB | Wtl 16.8MB | Xph 10MB | Xpl 10MB
    constexpr size_t FLAGRES = 1u << 20;
    constexpr size_t HSZ = (size_t)L_ * HDEP * B_ * H_;   // shorts per H plane
    constexpr size_t XSZ = (size_t)T_ * B_ * H_;          // shorts per Xp plane
    unsigned* flags = (unsigned*)d_ws;
    short* Hh  = (short*)((char*)d_ws + FLAGRES);
    short* Hl  = Hh + HSZ;
    short* Wth = Hl + HSZ;
    short* Wtl = Wth + (size_t)NMAT2 * MATSZ;
    short* Xph = Wtl + (size_t)NMAT2 * MATSZ;
    short* Xpl = Xph + XSZ;

    hipMemsetAsync(d_ws, 0, FLAGRES + 2 * HSZ * sizeof(short), stream);

    prep_kernel<<<dim3(16, 4, 31), 256, 0, stream>>>(Wih, Whh, Wth, Wtl);
    prep_w0<<<dim3(G4), 256, 0, stream>>>(Wih0, Wth, Wtl);
    prep_x<<<dim3(T_), 256, 0, stream>>>(seq, Xph, Xpl);

    hipFuncSetAttribute((const void*)wave_kernel,
                        hipFuncAttributeMaxDynamicSharedMemorySize, DYNLDS);
    wave_kernel<<<dim3(NBLK), dim3(256), DYNLDS, stream>>>(
        Wth, Wtl, Xph, Xpl, bias, gih, bih, ghh, bhh, gc, bc, Hh, Hl, flags);

    final_kernel<<<B_, 256, 0, stream>>>(Hh, Hl, Wlin, blin, out);
}

// Round 11
// 3545.132 us; speedup vs baseline: 1.6992x; 1.0536x over previous
//
#include <hip/hip_runtime.h>

typedef short s16x8 __attribute__((ext_vector_type(8)));
typedef float f32x4 __attribute__((ext_vector_type(4)));

constexpr int B_  = 128;
constexpr int T_  = 152;
constexpr int I_  = 75;
constexpr int H_  = 256;
constexpr int L_  = 16;
constexpr int C_  = 625;
constexpr int G4  = 1024;          // 4*H
constexpr float EPS_ = 1e-5f;
constexpr int NBLK = 256;          // 16 layers x 16 col-groups
constexpr int ND  = T_ + L_ - 1;   // 167 diagonals
constexpr int NMAT2 = 32;          // 15 W_ih + 16 W_hh + 1 W0^T(padded)
constexpr size_t MATSZ = (size_t)G4 * H_;
constexpr int HDEP = 8;            // H rotation depth (WAR slack 7)
constexpr int XK   = 96;           // padded K for layer-0 input (75 -> 96)

constexpr int WSTRIDE = 266;               // odd dword stride -> <=2-way LDS conflicts
constexpr int WPL_SH  = 64 * WSTRIDE;      // shorts per W plane in LDS (17024)
constexpr int DYNLDS  = 4 * WPL_SH * 2;    // 136192 B dynamic arena

__device__ __forceinline__ f32x4 mfma16(s16x8 a, s16x8 b, f32x4 c) {
    return __builtin_amdgcn_mfma_f32_16x16x32_bf16(a, b, c, 0, 0, 0);
}
__device__ __forceinline__ float sigm(float x) { return 1.f / (1.f + expf(-x)); }
__device__ __forceinline__ short f2bf(float x) {
    __bf16 h = (__bf16)x; return __builtin_bit_cast(short, h);
}
__device__ __forceinline__ float bf2f(short s) {
    __bf16 h = __builtin_bit_cast(__bf16, s); return (float)h;
}

// A-load: L2=true -> sc0 (bypass L1, hit XCD-local L2); false -> sc0 sc1 (LLC)
template<bool L2>
__device__ __forceinline__ s16x8 ldA(const short* p) {
    s16x8 r;
    if constexpr (L2)
        asm volatile("global_load_dwordx4 %0, %1, off sc0" : "=v"(r) : "v"(p));
    else
        asm volatile("global_load_dwordx4 %0, %1, off sc0 sc1" : "=v"(r) : "v"(p));
    return r;
}
__device__ __forceinline__ void stg_dc16(short* p, short v) {
    asm volatile("global_store_short %0, %1, off sc0 sc1" :: "v"(p), "v"(v));
}
__device__ __forceinline__ unsigned ldf_dc(const unsigned* p) {
    unsigned v;
    asm volatile("global_load_dword %0, %1, off sc0 sc1\n\ts_waitcnt vmcnt(0)"
                 : "=v"(v) : "v"(p));
    return v;
}
#define VMW4(N, a,b,c,d)                                                     \
    asm volatile("s_waitcnt vmcnt(" N ")"                                    \
                 : "+v"(a), "+v"(b), "+v"(c), "+v"(d))

// one 128B line (32 dwords) per (layer, diagonal); word g = producer gq's flag
__device__ __forceinline__ unsigned* flagline(unsigned* flags, int l, int dd) {
    return flags + (size_t)(l * ND + dd) * 32;
}
__device__ __forceinline__ int baseof(int L) {
    return ((L >> 1) & 7) | ((L & 1) << 3);
}

// all threads call; lanes 0-15 of each wave poll one 128B flag line
__device__ __forceinline__ void poll_line(const unsigned* line, int lane) {
    const unsigned* a = (lane < 16) ? (line + lane) : nullptr;
    bool done = (a == nullptr);
    if (!done) done = (ldf_dc(a) != 0u);
    while (!__all(done)) {
        __builtin_amdgcn_s_sleep(2);
        if (!done) done = (ldf_dc(a) != 0u);
    }
}

// ---------------------------------------------------------------------------
// Prep kernels (transpose + hi/lo bf16 split)
// ---------------------------------------------------------------------------
__global__ void __launch_bounds__(256)
prep_kernel(const float* __restrict__ Wih, const float* __restrict__ Whh,
            short* __restrict__ Wth, short* __restrict__ Wtl) {
    __shared__ float tile[64][65];
    const int mat = blockIdx.z;
    const int n0  = blockIdx.x * 64;
    const int k0  = blockIdx.y * 64;
    const int tid = threadIdx.x;
    const float* src = (mat < 15) ? (Wih + (size_t)mat * MATSZ)
                                  : (Whh + (size_t)(mat - 15) * MATSZ);
#pragma unroll
    for (int r = 0; r < 16; ++r) {
        int idx = r * 256 + tid;
        int kk = idx >> 6, nn = idx & 63;
        tile[kk][nn] = src[(size_t)(k0 + kk) * G4 + n0 + nn];
    }
    __syncthreads();
#pragma unroll
    for (int r = 0; r < 16; ++r) {
        int idx = r * 256 + tid;
        int nn = idx >> 6, kk = idx & 63;
        float w = tile[kk][nn];
        short hi = f2bf(w);
        short lo = f2bf(w - bf2f(hi));
        size_t o = ((size_t)mat * G4 + n0 + nn) * H_ + k0 + kk;
        Wth[o] = hi;
        Wtl[o] = lo;
    }
}

__global__ void __launch_bounds__(256)
prep_w0(const float* __restrict__ Wih0, short* __restrict__ Wth, short* __restrict__ Wtl) {
    const int n = blockIdx.x;
    const int k = threadIdx.x;
    float w = (k < I_) ? Wih0[(size_t)k * G4 + n] : 0.f;
    short hi = f2bf(w);
    short lo = f2bf(w - bf2f(hi));
    size_t o = ((size_t)31 * G4 + n) * H_ + k;
    Wth[o] = hi;
    Wtl[o] = lo;
}

__global__ void __launch_bounds__(256)
prep_x(const float* __restrict__ seq, short* __restrict__ Xph, short* __restrict__ Xpl) {
    const int t = blockIdx.x;
    for (int idx = threadIdx.x; idx < B_ * XK; idx += 256) {
        int row = idx / XK, k = idx - row * XK;
        float v = (k < I_) ? seq[(size_t)row * T_ * I_ + (size_t)t * I_ + k] : 0.f;
        short hi = f2bf(v);
        short lo = f2bf(v - bf2f(hi));
        size_t o = ((size_t)t * B_ + row) * XK + k;
        Xph[o] = hi;
        Xpl[o] = lo;
    }
}

// ---------------------------------------------------------------------------
// Half-GEMM: one operand pair (X hi/lo planes), K = nks*32, W from LDS.
// 2-deep software pipeline, load path selected by template (L2 vs LLC).
// ---------------------------------------------------------------------------
template<bool L2>
__device__ __forceinline__ void gemm_half(
    const short* __restrict__ Xh, const short* __restrict__ Xl, int xis, int nks,
    const short* __restrict__ Wh_lds, const short* __restrict__ Wl_lds,
    int arow0, int koff, int lcol, f32x4 acc[2][4]) {
#pragma unroll
    for (int mt = 0; mt < 2; ++mt)
#pragma unroll
        for (int g = 0; g < 4; ++g) acc[mt][g] = (f32x4){0.f, 0.f, 0.f, 0.f};

    const short* ph0 = Xh + (size_t)arow0 * xis + koff;
    const short* ph1 = ph0 + 16 * xis;
    const short* pl0 = Xl + (size_t)arow0 * xis + koff;
    const short* pl1 = pl0 + 16 * xis;

    s16x8 c0h = ldA<L2>(ph0), c1h = ldA<L2>(ph1);
    s16x8 c0l = ldA<L2>(pl0), c1l = ldA<L2>(pl1);
    s16x8 d0h, d1h, d0l, d1l;
    d0h = ldA<L2>(ph0 + 32); d1h = ldA<L2>(ph1 + 32);
    d0l = ldA<L2>(pl0 + 32); d1l = ldA<L2>(pl1 + 32);

    for (int ks = 0; ks < nks; ++ks) {
        s16x8 e0h, e1h, e0l, e1l;
        if (ks + 2 < nks) {
            const int ko = (ks + 2) * 32;
            e0h = ldA<L2>(ph0 + ko); e1h = ldA<L2>(ph1 + ko);
            e0l = ldA<L2>(pl0 + ko); e1l = ldA<L2>(pl1 + ko);
            VMW4("8", c0h, c1h, c0l, c1l);
        } else if (ks + 1 < nks) {
            VMW4("4", c0h, c1h, c0l, c1l);
        } else {
            VMW4("0", c0h, c1h, c0l, c1l);
        }
#pragma unroll
        for (int g = 0; g < 4; ++g) {
            const int bo = (g * 16 + lcol) * WSTRIDE + ks * 32 + koff;
            s16x8 bh = *(const s16x8*)&Wh_lds[bo];
            s16x8 bl = *(const s16x8*)&Wl_lds[bo];
            acc[0][g] = mfma16(c0h, bh, acc[0][g]);
            acc[0][g] = mfma16(c0l, bh, acc[0][g]);
            acc[0][g] = mfma16(c0h, bl, acc[0][g]);
            acc[0][g] = mfma16(c0l, bl, acc[0][g]);
            acc[1][g] = mfma16(c1h, bh, acc[1][g]);
            acc[1][g] = mfma16(c1l, bh, acc[1][g]);
            acc[1][g] = mfma16(c1h, bl, acc[1][g]);
            acc[1][g] = mfma16(c1l, bl, acc[1][g]);
        }
        c0h = d0h; c1h = d1h; c0l = d0l; c1l = d1l;
        d0h = e0h; d1h = e1h; d0l = e0l; d1l = e1l;
    }
}

// BN stats for 8 groups (4 input, 4 recurrent), 4 waves, mt=2 tiles.
__device__ __forceinline__ void bn_stats8(
    const f32x4 aI[2][4], const f32x4 aR[2][4], int tid,
    float (*redS)[4][16], float (*redQ)[4][16],
    float (*mvM)[16], float (*mvI)[16]) {
    const int lane = tid & 63;
    const int wv   = tid >> 6;
    const int lcol = lane & 15;
#pragma unroll
    for (int g = 0; g < 8; ++g) {
        float s = 0.f, q = 0.f;
#pragma unroll
        for (int mt = 0; mt < 2; ++mt) {
            const f32x4& v = (g < 4) ? aI[mt][g] : aR[mt][g - 4];
#pragma unroll
            for (int r = 0; r < 4; ++r) { float a = v[r]; s += a; q += a * a; }
        }
        s += __shfl_xor(s, 16); s += __shfl_xor(s, 32);
        q += __shfl_xor(q, 16); q += __shfl_xor(q, 32);
        if (lane < 16) { redS[g][wv][lcol] = s; redQ[g][wv][lcol] = q; }
    }
    __syncthreads();
    if (tid < 128) {
        int g = tid >> 4, c = tid & 15;
        float s = redS[g][0][c] + redS[g][1][c] + redS[g][2][c] + redS[g][3][c];
        float q = redQ[g][0][c] + redQ[g][1][c] + redQ[g][2][c] + redQ[g][3][c];
        float m = s * (1.0f / B_);
        float v = q * (1.0f / B_) - m * m;
        mvM[g][c] = m;
        mvI[g][c] = rsqrtf(fmaxf(v, 0.f) + EPS_);
    }
    __syncthreads();
}

// ---------------------------------------------------------------------------
// Wavefront kernel. Runtime XCD discovery selects XCD-local-L2 vs LLC paths
// per dependency edge (correct under ANY workgroup->XCD mapping).
// ---------------------------------------------------------------------------
__global__ void __launch_bounds__(256, 1)
wave_kernel(const short* __restrict__ Wth, const short* __restrict__ Wtl,
            const short* __restrict__ Xph, const short* __restrict__ Xpl,
            const float* __restrict__ bias,
            const float* __restrict__ g_ih, const float* __restrict__ b_ih,
            const float* __restrict__ g_hh, const float* __restrict__ b_hh,
            const float* __restrict__ g_c,  const float* __restrict__ b_c,
            short* __restrict__ Hh, short* __restrict__ Hl,
            short* __restrict__ Rh, short* __restrict__ Rl,
            unsigned* __restrict__ flags) {
    extern __shared__ char arena[];
    __shared__ float redS[8][4][16];
    __shared__ float redQ[8][4][16];
    __shared__ float mvM[8][16], mvI[8][16];
    __shared__ float cms[16], cis[16];
    __shared__ unsigned s_mode;

    short* Wr_hi = (short*)arena;
    short* Wr_lo = Wr_hi + WPL_SH;
    short* Wi_hi = Wr_lo + WPL_SH;
    short* Wi_lo = Wi_hi + WPL_SH;

    const int b    = blockIdx.x;
    const int l    = ((b & 7) << 1) | ((b >> 3) & 1);
    const int gq   = b >> 4;
    const int j0   = gq * 16;
    const int tid  = threadIdx.x;
    const int lane = tid & 63;
    const int wv   = tid >> 6;
    const int quad = lane >> 4;
    const int lcol = lane & 15;
    const int jc   = j0 + lcol;

    // ---- runtime XCD discovery ----
    unsigned* xcdmap = flags + 131072;      // byte offset 512KB
    unsigned* startc = xcdmap + 512;
    unsigned myx;
    asm volatile("s_getreg_b32 %0, hwreg(HW_REG_XCC_ID)" : "=s"(myx));
    if (tid == 0) {
        unsigned* mp = xcdmap + b;
        unsigned v = myx + 1u;
        asm volatile("global_store_dword %0, %1, off sc0 sc1" :: "v"(mp), "v"(v) : "memory");
        asm volatile("s_waitcnt vmcnt(0)");
        __hip_atomic_fetch_add(startc, 1u, __ATOMIC_RELAXED, __HIP_MEMORY_SCOPE_AGENT);
        while (ldf_dc(startc) < (unsigned)NBLK) __builtin_amdgcn_s_sleep(4);
    }
    __syncthreads();
    if (wv == 0) {
        const int li = lane >> 4, gi = lane & 15;
        int peerb = -1;
        if (li == 0)               peerb = baseof(l) + 16 * gi;
        else if (li == 1 && l > 0) peerb = baseof(l - 1) + 16 * gi;
        else if (li == 2 && l < 15) peerb = baseof(l + 1) + 16 * gi;
        bool eq = true;
        if (peerb >= 0) eq = (ldf_dc(xcdmap + peerb) == myx + 1u);
        unsigned long long m = __ballot(eq);
        if (lane == 0) {
            bool sL  = ((m & 0xFFFFull) == 0xFFFFull);
            bool sIm = (l == 0) ? true : (((m >> 16) & 0xFFFFull) == 0xFFFFull);
            bool sUp = (l == 15) ? true : (((m >> 32) & 0xFFFFull) == 0xFFFFull);
            s_mode = (sL ? 1u : 0u) | (sIm ? 2u : 0u) | ((sL && sUp) ? 4u : 0u);
        }
    }
    __syncthreads();
    const unsigned mode = s_mode;
    const bool xrl2  = (mode & 1u) != 0;
    const bool xil2  = (mode & 2u) != 0;
    const bool skipdc = (mode & 4u) != 0;

    float gihv[4], bihv[4], ghhv[4], bhhv[4], bsv[4];
#pragma unroll
    for (int g = 0; g < 4; ++g) {
        int col = l * G4 + g * H_ + jc;
        gihv[g] = g_ih[col];
        bihv[g] = b_ih[col];
        ghhv[g] = g_hh[col];
        bhhv[g] = b_hh[col];
        bsv[g]  = bias[col];
    }
    const float gcv = g_c[l * H_ + jc];
    const float bcv = b_c[l * H_ + jc];

    // ---- persistent weight preload (once) ----
    {
        const int row = tid >> 2, seg = (tid & 3) * 64;
        const int g = row >> 4, c = row & 15;
        const size_t srow = ((size_t)(g * H_ + j0 + c)) * H_ + seg;
        const int miI = (l > 0) ? (l - 1) : 31;
        const short* sWrh = Wth + (size_t)(15 + l) * MATSZ + srow;
        const short* sWrl = Wtl + (size_t)(15 + l) * MATSZ + srow;
        const short* sWih = Wth + (size_t)miI * MATSZ + srow;
        const short* sWil = Wtl + (size_t)miI * MATSZ + srow;
        short* dWrh = Wr_hi + row * WSTRIDE + seg;
        short* dWrl = Wr_lo + row * WSTRIDE + seg;
        short* dWih = Wi_hi + row * WSTRIDE + seg;
        short* dWil = Wi_lo + row * WSTRIDE + seg;
#pragma unroll
        for (int u = 0; u < 8; ++u) {
            *(s16x8*)(dWrh + u * 8) = *(const s16x8*)(sWrh + u * 8);
            *(s16x8*)(dWrl + u * 8) = *(const s16x8*)(sWrl + u * 8);
            *(s16x8*)(dWih + u * 8) = *(const s16x8*)(sWih + u * 8);
            *(s16x8*)(dWil + u * 8) = *(const s16x8*)(sWil + u * 8);
        }
    }
    __syncthreads();

    f32x4 creg[2];
    creg[0] = (f32x4){0.f, 0.f, 0.f, 0.f};
    creg[1] = (f32x4){0.f, 0.f, 0.f, 0.f};

    const int arow0 = wv * 32 + lcol;
    const int koff  = quad * 8;

    for (int t = 0; t < T_; ++t) {
        const int d  = t + l;
        const int pr = (d - 1) & (HDEP - 1);
        const int pw = d & (HDEP - 1);

        f32x4 accI[2][4], accR[2][4];

        // ---- wait own-layer peers (XR ready), then R-GEMM ----
        if (t >= 1) poll_line(flagline(flags, l, d - 1), lane);
        {
            const size_t so = (size_t)(l * HDEP + pr) * B_ * H_;
            if (xrl2) gemm_half<true >(Rh + so, Rl + so, H_, 8, Wr_hi, Wr_lo,
                                       arow0, koff, lcol, accR);
            else      gemm_half<false>(Hh + so, Hl + so, H_, 8, Wr_hi, Wr_lo,
                                       arow0, koff, lcol, accR);
        }

        // ---- wait layer l-1 (XI ready; detect hidden under R-GEMM), I-GEMM ----
        if (l > 0) {
            poll_line(flagline(flags, l - 1, d - 1), lane);
            const size_t so = (size_t)((l - 1) * HDEP + pr) * B_ * H_;
            if (xil2) gemm_half<true >(Rh + so, Rl + so, H_, 8, Wi_hi, Wi_lo,
                                       arow0, koff, lcol, accI);
            else      gemm_half<false>(Hh + so, Hl + so, H_, 8, Wi_hi, Wi_lo,
                                       arow0, koff, lcol, accI);
        } else {
            const size_t so = (size_t)t * B_ * XK;
            gemm_half<true>(Xph + so, Xpl + so, XK, 3, Wi_hi, Wi_lo,
                            arow0, koff, lcol, accI);
        }

        // ---- BN stats (both GEMMs, one pass) ----
        bn_stats8(accI, accR, tid, redS, redQ, mvM, mvI);

        f32x4 osv[2];
#pragma unroll
        for (int mt = 0; mt < 2; ++mt) {
#pragma unroll
            for (int r = 0; r < 4; ++r) {
                float bn0 = (accI[mt][0][r] - mvM[0][lcol]) * mvI[0][lcol] * gihv[0] + bihv[0];
                float bn1 = (accI[mt][1][r] - mvM[1][lcol]) * mvI[1][lcol] * gihv[1] + bihv[1];
                float bn2 = (accI[mt][2][r] - mvM[2][lcol]) * mvI[2][lcol] * gihv[2] + bihv[2];
                float bn3 = (accI[mt][3][r] - mvM[3][lcol]) * mvI[3][lcol] * gihv[3] + bihv[3];
                float sf = (accR[mt][0][r] - mvM[4][lcol]) * mvI[4][lcol] * ghhv[0] + bhhv[0] + bn0 + bsv[0];
                float si = (accR[mt][1][r] - mvM[5][lcol]) * mvI[5][lcol] * ghhv[1] + bhhv[1] + bn1 + bsv[1];
                float so = (accR[mt][2][r] - mvM[6][lcol]) * mvI[6][lcol] * ghhv[2] + bhhv[2] + bn2 + bsv[2];
                float sg = (accR[mt][3][r] - mvM[7][lcol]) * mvI[7][lcol] * ghhv[3] + bhhv[3] + bn3 + bsv[3];
                creg[mt][r] = sigm(sf) * creg[mt][r] + sigm(si) * tanhf(sg);
                osv[mt][r]  = so;
            }
        }

        // ---- BN over c ----
        {
            float s = 0.f, q = 0.f;
#pragma unroll
            for (int mt = 0; mt < 2; ++mt)
#pragma unroll
                for (int r = 0; r < 4; ++r) { float a = creg[mt][r]; s += a; q += a * a; }
            s += __shfl_xor(s, 16); s += __shfl_xor(s, 32);
            q += __shfl_xor(q, 16); q += __shfl_xor(q, 32);
            if (lane < 16) { redS[0][wv][lcol] = s; redQ[0][wv][lcol] = q; }
        }
        __syncthreads();
        if (tid < 16) {
            float s = redS[0][0][tid] + redS[0][1][tid] + redS[0][2][tid] + redS[0][3][tid];
            float q = redQ[0][0][tid] + redQ[0][1][tid] + redQ[0][2][tid] + redQ[0][3][tid];
            float m = s * (1.0f / B_);
            float v = q * (1.0f / B_) - m * m;
            cms[tid] = m;
            cis[tid] = rsqrtf(fmaxf(v, 0.f) + EPS_);
        }
        __syncthreads();

        // ---- WAR wait (deferred; rarely binds), then dual-store H ----
        if (l < 15 && t >= HDEP)
            poll_line(flagline(flags, l + 1, d - (HDEP - 1)), lane);
        {
            const float m = cms[lcol], is = cis[lcol];
            const size_t so = (size_t)(l * HDEP + pw) * B_ * H_;
            short* Rwh = Rh + so; short* Rwl = Rl + so;
            short* Hwh = Hh + so; short* Hwl = Hl + so;
#pragma unroll
            for (int mt = 0; mt < 2; ++mt)
#pragma unroll
                for (int r = 0; r < 4; ++r) {
                    int row = wv * 32 + mt * 16 + quad * 4 + r;
                    float hv = sigm(osv[mt][r]) * tanhf((creg[mt][r] - m) * is * gcv + bcv);
                    short hi = f2bf(hv);
                    short lo = f2bf(hv - bf2f(hi));
                    size_t off = (size_t)row * H_ + jc;
                    Rwh[off] = hi;               // plain: local-L2 resident (always)
                    Rwl[off] = lo;
                    if (!skipdc) {               // LLC copy for remote readers
                        stg_dc16(&Hwh[off], hi);
                        stg_dc16(&Hwl[off], lo);
                    }
                }
        }
        __syncthreads();   // drains vmcnt in every wave -> stores complete
        if (tid == 0) {
            unsigned* p = flagline(flags, l, d) + gq;
            asm volatile("global_store_dword %0, %1, off sc0 sc1"
                         :: "v"(p), "v"(1u) : "memory");
        }
    }
}

// ---------------------------------------------------------------------------
// Final linear + softmax: one WG per batch row.
// Reads Rh/Rl (ALWAYS written; Hh/Hl is skipped when consumers are XCD-local).
// Kernel-boundary release/acquire makes Rh/Rl visible across dispatches.
// ---------------------------------------------------------------------------
__global__ void __launch_bounds__(256)
final_kernel(const short* __restrict__ Rh, const short* __restrict__ Rl,
             const float* __restrict__ Wlin, const float* __restrict__ blin,
             float* __restrict__ out) {
    const int b   = blockIdx.x;
    const int tid = threadIdx.x;
    __shared__ float hs[H_];
    __shared__ float rbuf[256];
    constexpr int lastPar = (ND - 1) & (HDEP - 1);  // = 6

    {
        size_t o = (size_t)((L_ - 1) * HDEP + lastPar) * B_ * H_ + (size_t)b * H_ + tid;
        hs[tid] = bf2f(Rh[o]) + bf2f(Rl[o]);
    }
    __syncthreads();

    float lg[3];
#pragma unroll
    for (int r = 0; r < 3; ++r) {
        int cls = tid + r * 256;
        float a = -1e30f;
        if (cls < C_) {
            a = blin[cls];
            for (int j = 0; j < H_; ++j) a += hs[j] * Wlin[(size_t)j * C_ + cls];
        }
        lg[r] = a;
    }

    float mx = fmaxf(fmaxf(lg[0], lg[1]), lg[2]);
    rbuf[tid] = mx;
    __syncthreads();
    for (int s = 128; s > 0; s >>= 1) {
        if (tid < s) rbuf[tid] = fmaxf(rbuf[tid], rbuf[tid + s]);
        __syncthreads();
    }
    mx = rbuf[0];
    __syncthreads();

    float ev[3];
    float es = 0.f;
#pragma unroll
    for (int r = 0; r < 3; ++r) {
        int cls = tid + r * 256;
        if (cls < C_) { ev[r] = expf(lg[r] - mx); es += ev[r]; }
        else ev[r] = 0.f;
    }
    rbuf[tid] = es;
    __syncthreads();
    for (int s = 128; s > 0; s >>= 1) {
        if (tid < s) rbuf[tid] += rbuf[tid + s];
        __syncthreads();
    }
    const float inv = 1.f / rbuf[0];
#pragma unroll
    for (int r = 0; r < 3; ++r) {
        int cls = tid + r * 256;
        if (cls < C_) out[(size_t)b * C_ + cls] = ev[r] * inv;
    }
}

// ---------------------------------------------------------------------------
extern "C" void kernel_launch(void* const* d_in, const int* in_sizes, int n_in,
                              void* d_out, int out_size, void* d_ws, size_t ws_size,
                              hipStream_t stream) {
    const float* seq  = (const float*)d_in[0];
    const float* Wih0 = (const float*)d_in[1];
    const float* Wih  = (const float*)d_in[2];
    const float* Whh  = (const float*)d_in[3];
    const float* bias = (const float*)d_in[4];
    const float* gih  = (const float*)d_in[5];
    const float* bih  = (const float*)d_in[6];
    const float* ghh  = (const float*)d_in[7];
    const float* bhh  = (const float*)d_in[8];
    const float* gc   = (const float*)d_in[9];
    const float* bc   = (const float*)d_in[10];
    const float* Wlin = (const float*)d_in[11];
    const float* blin = (const float*)d_in[12];
    float* out = (float*)d_out;

    // ws: flags+map 1MB | Hh,Hl,Rh,Rl 4x8MB | Wth,Wtl 2x16.8MB | Xph,Xpl 2x3.6MB
    constexpr size_t FLAGRES = 1u << 20;
    constexpr size_t HSZ = (size_t)L_ * HDEP * B_ * H_;   // shorts per plane
    constexpr size_t XSZ = (size_t)T_ * B_ * XK;
    unsigned* flags = (unsigned*)d_ws;
    short* Hh  = (short*)((char*)d_ws + FLAGRES);
    short* Hl  = Hh + HSZ;
    short* Rh  = Hl + HSZ;
    short* Rl  = Rh + HSZ;
    short* Wth = Rl + HSZ;
    short* Wtl = Wth + (size_t)NMAT2 * MATSZ;
    short* Xph = Wtl + (size_t)NMAT2 * MATSZ;
    short* Xpl = Xph + XSZ;

    hipMemsetAsync(d_ws, 0, FLAGRES + 4 * HSZ * sizeof(short), stream);

    prep_kernel<<<dim3(16, 4, 31), 256, 0, stream>>>(Wih, Whh, Wth, Wtl);
    prep_w0<<<dim3(G4), 256, 0, stream>>>(Wih0, Wth, Wtl);
    prep_x<<<dim3(T_), 256, 0, stream>>>(seq, Xph, Xpl);

    hipFuncSetAttribute((const void*)wave_kernel,
                        hipFuncAttributeMaxDynamicSharedMemorySize, DYNLDS);
    wave_kernel<<<dim3(NBLK), dim3(256), DYNLDS, stream>>>(
        Wth, Wtl, Xph, Xpl, bias, gih, bih, ghh, bhh, gc, bc,
        Hh, Hl, Rh, Rl, flags);

    final_kernel<<<B_, 256, 0, stream>>>(Rh, Rl, Wlin, blin, out);
}